// Round 12
// baseline (1658.473 us; speedup 1.0000x reference)
//
#include <hip/hip_runtime.h>
#include <cstdint>
#include <cstddef>

using bf16 = __bf16;
typedef __bf16 bf16x8 __attribute__((ext_vector_type(8)));
typedef __bf16 bf16x4 __attribute__((ext_vector_type(4)));
typedef __bf16 bf16x2 __attribute__((ext_vector_type(2)));
typedef float  f32x4  __attribute__((ext_vector_type(4)));
typedef float  f32x16 __attribute__((ext_vector_type(16)));
typedef int    i32x4  __attribute__((ext_vector_type(4)));
typedef float  f32x4u __attribute__((ext_vector_type(4), aligned(4)));  // 4B-aligned vec load

// ---- problem constants ----
constexpr int NB   = 2;      // batch
constexpr int NN   = 2048;   // seq
constexpr int DIM  = 1024;
constexpr int NH   = 8;
constexpr int DH   = 64;
constexpr int INNER= 512;
constexpr int QKVN = 640;    // fused Q(512) + K(64) + V(64) projection width
constexpr int FF   = 2730;
constexpr int FFP  = 2816;   // padded FF (22*128)
constexpr int FF2N = 5632;   // fused a|g FF1 output width (interleaved 32-groups)
constexpr int MROW = NB * NN;   // 4096
constexpr int NLAY = 6;
constexpr int AROWS = NB * NH * NN;  // 32768 attention (b,h,q) rows
constexpr int NSPLIT = 4;            // KV splits

// async global->LDS, 16B per lane; LDS dest is wave-uniform base (+lane*16 by HW)
__device__ __forceinline__ void gload_lds16(const bf16* g, bf16* l) {
  __builtin_amdgcn_global_load_lds((const __attribute__((address_space(1))) void*)g,
                                   (__attribute__((address_space(3))) void*)l,
                                   16, 0, 0);
}

__device__ __forceinline__ int pack_bf16(float lo, float hi_) {
  bf16x2 t; t[0] = (bf16)lo; t[1] = (bf16)hi_;
  return __builtin_bit_cast(int, t);
}

// ======================= bias table ==========================
__global__ void btab_kernel(const float* __restrict__ rel, float* __restrict__ btab) {
  int d = blockIdx.x * 256 + threadIdx.x;
  if (d >= NN) return;
  int bucket;
  if (d < 16) bucket = d;
  else {
    int vl = 16 + (int)(logf((float)d / 16.0f) / logf(8.0f) * 16.0f);
    bucket = vl < 31 ? vl : 31;
  }
  for (int h = 0; h < NH; ++h) btab[h * NN + d] = rel[bucket * NH + h];
}

// ============== weight convert + transpose (+pad, +scale, +row-remap) ==============
// rowOff16 < 0: dst row = i.  rowOff16 >= 0: dst row = ((i>>4)<<5) + rowOff16 + (i&15)
// (interleaves two sources into 32-row groups: a rows at +0, g rows at +16).
__global__ void conv_tr(const float* __restrict__ src, size_t srcLayer, int srcStride,
                        int colOff, int R, int C,
                        bf16* __restrict__ dst, size_t dstLayer, int Tcols, float scale,
                        int rowOff16) {
  __shared__ float tile[32][33];
  const int i0 = blockIdx.x * 32, j0 = blockIdx.y * 32, z = blockIdx.z;
  const float* s = src + (size_t)z * srcLayer;
  bf16* d = dst + (size_t)z * dstLayer;
  const int tx = threadIdx.x, ty = threadIdx.y;
#pragma unroll
  for (int k = 0; k < 4; ++k) {
    int j = j0 + ty + k * 8;
    int i = i0 + tx;
    float v = 0.0f;
    if (j < R && i < C) v = s[(size_t)j * srcStride + colOff + i] * scale;
    tile[ty + k * 8][tx] = v;
  }
  __syncthreads();
#pragma unroll
  for (int k = 0; k < 4; ++k) {
    int i = i0 + ty + k * 8;   // logical dst row
    int j = j0 + tx;           // dst col
    int dr = (rowOff16 >= 0) ? (((i >> 4) << 5) + rowOff16 + (i & 15)) : i;
    d[(size_t)dr * Tcols + j] = (bf16)tile[tx][ty + k * 8];
  }
}

// ======================= LayerNorm ==========================
template <typename OUT>
__global__ void ln_kernel(const float* __restrict__ X, const float* __restrict__ G,
                          const float* __restrict__ Bt, OUT* __restrict__ out) {
  __shared__ float red[8];
  const int row = blockIdx.x, t = threadIdx.x;
  const float* xr = X + (size_t)row * DIM;
  float4 v = *(const float4*)(xr + t * 4);
  float s  = v.x + v.y + v.z + v.w;
  float s2 = v.x * v.x + v.y * v.y + v.z * v.z + v.w * v.w;
#pragma unroll
  for (int o = 1; o < 64; o <<= 1) { s += __shfl_xor(s, o); s2 += __shfl_xor(s2, o); }
  if ((t & 63) == 0) { red[t >> 6] = s; red[4 + (t >> 6)] = s2; }
  __syncthreads();
  float S  = red[0] + red[1] + red[2] + red[3];
  float S2 = red[4] + red[5] + red[6] + red[7];
  const float inv = 1.0f / (float)DIM;
  float mu = S * inv;
  float var = S2 * inv - mu * mu;
  float rstd = rsqrtf(var + 1e-5f);
  float4 g  = *(const float4*)(G + t * 4);
  float4 bb = *(const float4*)(Bt + t * 4);
  OUT* orow = out + (size_t)row * DIM + t * 4;
  orow[0] = (OUT)((v.x - mu) * rstd * g.x + bb.x);
  orow[1] = (OUT)((v.y - mu) * rstd * g.y + bb.y);
  orow[2] = (OUT)((v.z - mu) * rstd * g.z + bb.z);
  orow[3] = (OUT)((v.w - mu) * rstd * g.w + bb.w);
}

// ======================= GEMM (r6 core, for N<=1024 shapes) ==========================
// 128x128 tile, BK=64, 8 waves (2Mx4N, 64x32 each), double-buffered LDS (64KB),
// prefetch distance 1, 2 barriers/K-step. Needs 2 blocks/CU for latency hiding.
// MODE 0: store bf16 C. MODE 1: Xr += acc (fp32 residual, gridDim.z==1).
// MODE 3: split-K over gridDim.z -- each z-block does K/nz, atomicAdd into Xr
//         (device-scope fp32 atomics, distinct addrs; raises grid to 2 blocks/CU
//         for the 256-block shapes WO/FF2).
template <int MODE>
__launch_bounds__(512)
__global__ void gemm_bt(const bf16* __restrict__ A, const bf16* __restrict__ B,
                        int K, int lda, int N, bf16* __restrict__ Cb, float* __restrict__ Xr) {
  __shared__ __align__(16) bf16 As[2][128 * 64];
  __shared__ __align__(16) bf16 Bs[2][128 * 64];
  const int tid = threadIdx.x;
  const int lane = tid & 63, wave = tid >> 6;
  const int gx = gridDim.x, gy = gridDim.y;
  const int nwg = gx * gy;
  const int orig = blockIdx.y * gx + blockIdx.x;
  const int wgid = (orig & 7) * (nwg >> 3) + (orig >> 3);  // XCD swizzle (nwg%8==0)
  const int m0 = (wgid % gy) * 128;   // M fastest within XCD chunk -> B-panel L2 reuse
  const int n0 = (wgid / gy) * 128;
  const int ksub = K / gridDim.z;     // multiple of 64 for all our shapes
  const int kb = blockIdx.z * ksub;
  const int wm = (wave >> 2) * 64, wn = (wave & 3) * 32;
  const int fr = lane & 15, fg8 = (lane >> 4) * 8;
  const int frl8 = (fr & 7) * 8;           // read-side swizzle XOR
  const int rL = lane >> 3;                // staging row within 8-row group
  const int cS = ((lane & 7) ^ rL) * 8;    // pre-swizzled global source col
  const bf16* aB = A + (size_t)(m0 + wave * 8 + rL) * lda + cS;
  const bf16* bB = B + (size_t)(n0 + wave * 8 + rL) * K + cS;
  f32x4 acc[4][2] = {};

  auto STAGE = [&](int buf, int kt) {
#pragma unroll
    for (int r = 0; r < 2; ++r) {
      gload_lds16(aB + (size_t)(r * 64) * lda + kt, &As[buf][(r * 8 + wave) * 512]);
      gload_lds16(bB + (size_t)(r * 64) * K + kt, &Bs[buf][(r * 8 + wave) * 512]);
    }
  };

  STAGE(0, kb);
  const int nt = ksub >> 6;
  int cur = 0;
  for (int t = 0; t < nt; ++t) {
    asm volatile("s_waitcnt vmcnt(0)" ::: "memory");  // buf[cur] DMA (this wave) done
    __builtin_amdgcn_s_barrier();                     // all waves' DMA done
    __builtin_amdgcn_sched_barrier(0);
    if (t + 1 < nt) STAGE(cur ^ 1, kb + (t + 1) * 64);  // in flight across the compute
#pragma unroll
    for (int kk = 0; kk < 64; kk += 32) {
      bf16x8 af[4], bfr[2];
#pragma unroll
      for (int m = 0; m < 4; ++m)
        af[m] = *(const bf16x8*)&As[cur][(wm + m * 16 + fr) * 64 + ((kk + fg8) ^ frl8)];
#pragma unroll
      for (int n = 0; n < 2; ++n)
        bfr[n] = *(const bf16x8*)&Bs[cur][(wn + n * 16 + fr) * 64 + ((kk + fg8) ^ frl8)];
#pragma unroll
      for (int m = 0; m < 4; ++m)
#pragma unroll
        for (int n = 0; n < 2; ++n)
          acc[m][n] = __builtin_amdgcn_mfma_f32_16x16x32_bf16(af[m], bfr[n], acc[m][n], 0, 0, 0);
    }
    __builtin_amdgcn_sched_barrier(0);
    __builtin_amdgcn_s_barrier();                     // cur fully read; next STAGE may overwrite
    cur ^= 1;
  }
  const int cc = lane & 15, cg = (lane >> 4) * 4;
#pragma unroll
  for (int m = 0; m < 4; ++m) {
#pragma unroll
    for (int n = 0; n < 2; ++n) {
      const int col = n0 + wn + n * 16 + cc;
#pragma unroll
      for (int r = 0; r < 4; ++r) {
        const int row = m0 + wm + m * 16 + cg + r;
        const size_t idx = (size_t)row * N + col;
        if (MODE == 0)      Cb[idx] = (bf16)acc[m][n][r];
        else if (MODE == 1) Xr[idx] += acc[m][n][r];
        else                atomicAdd(&Xr[idx], acc[m][n][r]);
      }
    }
  }
}

// ======================= GEMM m97-structure (for FF1: large grid) ==================
// 128x128 tile, BK=64, 4 waves (2x2, 64x64 each, 4x4 acc), SINGLE 32KB LDS buffer,
// sync/stage/sync/compute. 3-4 co-resident blocks/CU hide the stage drain.
// MODE 2: GEGLU epilogue (B rows interleaved 32-groups: a@+0..15, g@+16..31);
// writes gelu(g)*a compact with row stride N (pass N=FFP).
template <int MODE>
__launch_bounds__(256)
__global__ void gemm97(const bf16* __restrict__ A, const bf16* __restrict__ B,
                       int K, int lda, int N, bf16* __restrict__ Cb, float* __restrict__ Xr) {
  __shared__ __align__(16) bf16 As[128 * 64];
  __shared__ __align__(16) bf16 Bs[128 * 64];
  const int tid = threadIdx.x;
  const int lane = tid & 63, wave = tid >> 6;
  const int gx = gridDim.x, gy = gridDim.y;
  const int nwg = gx * gy;
  const int orig = blockIdx.y * gx + blockIdx.x;
  const int wgid = (orig & 7) * (nwg >> 3) + (orig >> 3);  // XCD swizzle (nwg%8==0)
  const int m0 = (wgid % gy) * 128;
  const int n0 = (wgid / gy) * 128;
  const int wm = (wave >> 1) * 64, wn = (wave & 1) * 64;
  const int fr = lane & 15, fg8 = (lane >> 4) * 8;
  const int frl8 = (fr & 7) * 8;
  const int rL = lane >> 3;
  const int cS = ((lane & 7) ^ rL) * 8;
  const bf16* aB = A + (size_t)(m0 + wave * 8 + rL) * lda + cS;
  const bf16* bB = B + (size_t)(n0 + wave * 8 + rL) * K + cS;
  f32x4 acc[4][4] = {};

  for (int kt = 0; kt < K; kt += 64) {
    __syncthreads();   // previous compute done reading LDS
#pragma unroll
    for (int r = 0; r < 4; ++r) {
      gload_lds16(aB + (size_t)(r * 32) * lda + kt, &As[(r * 4 + wave) * 512]);
      gload_lds16(bB + (size_t)(r * 32) * K + kt, &Bs[(r * 4 + wave) * 512]);
    }
    __syncthreads();   // drains vmcnt(0): DMA complete (compiler-inserted)
#pragma unroll
    for (int kk = 0; kk < 64; kk += 32) {
      bf16x8 af[4], bfr[4];
#pragma unroll
      for (int m = 0; m < 4; ++m)
        af[m] = *(const bf16x8*)&As[(wm + m * 16 + fr) * 64 + ((kk + fg8) ^ frl8)];
#pragma unroll
      for (int n = 0; n < 4; ++n)
        bfr[n] = *(const bf16x8*)&Bs[(wn + n * 16 + fr) * 64 + ((kk + fg8) ^ frl8)];
#pragma unroll
      for (int m = 0; m < 4; ++m)
#pragma unroll
        for (int n = 0; n < 4; ++n)
          acc[m][n] = __builtin_amdgcn_mfma_f32_16x16x32_bf16(af[m], bfr[n], acc[m][n], 0, 0, 0);
    }
  }
  const int cc = lane & 15, cg = (lane >> 4) * 4;
  if (MODE == 2) {
    const int jbase = (n0 + wn) / 2 + cc;
#pragma unroll
    for (int m = 0; m < 4; ++m) {
#pragma unroll
      for (int p = 0; p < 2; ++p) {
#pragma unroll
        for (int r = 0; r < 4; ++r) {
          const int row = m0 + wm + m * 16 + cg + r;
          const float av = acc[m][2 * p][r], gv = acc[m][2 * p + 1][r];
          const float ge = 0.5f * gv * (1.0f + erff(gv * 0.70710678118654752f)) * av;
          Cb[(size_t)row * N + jbase + p * 16] = (bf16)ge;
        }
      }
    }
  } else {
#pragma unroll
    for (int m = 0; m < 4; ++m) {
#pragma unroll
      for (int n = 0; n < 4; ++n) {
        const int col = n0 + wn + n * 16 + cc;
#pragma unroll
        for (int r = 0; r < 4; ++r) {
          const int row = m0 + wm + m * 16 + cg + r;
          const size_t idx = (size_t)row * N + col;
          if (MODE == 0) Cb[idx] = (bf16)acc[m][n][r];
          else           Xr[idx] += acc[m][n][r];
        }
      }
    }
  }
}

// ======================= V transpose: VT[b][dh][n] = QKV[b*NN+n][576+dh] ==========
__global__ void vt_kernel(const bf16* __restrict__ QKV, bf16* __restrict__ VT) {
  __shared__ bf16 t[32][33];
  const int n0 = blockIdx.x * 32, d0 = blockIdx.y * 32, b = blockIdx.z;
  const int tx = threadIdx.x, ty = threadIdx.y;
#pragma unroll
  for (int k = 0; k < 4; ++k) {
    int n = n0 + ty + k * 8;
    t[ty + k * 8][tx] = QKV[(size_t)(b * NN + n) * QKVN + 576 + d0 + tx];
  }
  __syncthreads();
#pragma unroll
  for (int k = 0; k < 4; ++k) {
    int dh = d0 + ty + k * 8;
    VT[(size_t)(b * 64 + dh) * NN + n0 + tx] = t[tx][ty + k * 8];
  }
}

// ======================= attention: 32x32 MFMA, in-register softmax ==============
// 4 waves/block = 4 heads (MQA: K/V shared -> L1 reuse), no barriers, no LDS.
// NSPLIT=4 KV splits -> 1024 blocks = 4 waves/SIMD co-resident. Partials in
// q-major layout Opart[split][bh][q][64] so combine reads are coalesced.
__launch_bounds__(256)
__global__ void attn_kernel(const bf16* __restrict__ QKV, const bf16* __restrict__ VT,
                            const float* __restrict__ btab,
                            float* __restrict__ Opart, float* __restrict__ mlbuf) {
  const int tid = threadIdx.x;
  const int lane = tid & 63, wv = tid >> 6;
  const int split = blockIdx.x & (NSPLIT - 1);
  const int qt = (NN / 32 - 1) - (blockIdx.x / NSPLIT);   // longest-first
  const int h = blockIdx.y * 4 + wv, b = blockIdx.z;
  const int q0 = qt * 32;
  const int qc = lane & 31;        // q col (also A-operand row index, also V^T d row)
  const int hid = lane >> 5;
  const int h8 = hid * 8;
  const int kv_full = q0 + 32;
  // distribute 32-row tiles among NSPLIT splits
  const int nt32 = kv_full >> 5;
  const int base = nt32 >> 2, rem = nt32 & 3;
  const int cnt = base + (split < rem ? 1 : 0);
  const int startT = split * base + (split < rem ? split : rem);
  const int lo = startT * 32;
  const int kend = lo + cnt * 32;
  const size_t obase = ((size_t)(split * NB * NH) + b * NH + h) * NN;  // q-row base
  const int Rbase = (b * NH + h) * NN + q0;
  float* prow = Opart + (obase + q0 + qc) * 64;
  if (cnt == 0) {   // empty split: zero partial block, weight 0 in combine
#pragma unroll
    for (int dd = 0; dd < 32; ++dd) prow[dd * 2 + hid] = 0.0f;
    if (hid == 0)
      ((float2*)mlbuf)[(size_t)split * AROWS + Rbase + qc] = make_float2(-1e30f, 0.0f);
    return;
  }
  const float* bt = btab + h * NN;
  bf16x8 qf[4];
#pragma unroll
  for (int ks = 0; ks < 4; ++ks)
    qf[ks] = *(const bf16x8*)&QKV[(size_t)(b * NN + q0 + qc) * QKVN + h * DH + ks * 16 + h8];

  f32x16 Oacc0 = {}, Oacc1 = {};
  float m_run = -1e30f, l_run = 0.0f;
  int kv0 = lo;

  while (kv0 < kend) {
    const bool interior = (kv0 + 32 <= q0);
    bf16x8 kf[4];
#pragma unroll
    for (int ks = 0; ks < 4; ++ks)
      kf[ks] = *(const bf16x8*)&QKV[(size_t)(b * NN + kv0 + qc) * QKVN + 512 + ks * 16 + h8];
    bf16x8 vf[2][2];
#pragma unroll
    for (int dblk = 0; dblk < 2; ++dblk)
#pragma unroll
      for (int ks2 = 0; ks2 < 2; ++ks2)
        vf[dblk][ks2] = *(const bf16x8*)&VT[(size_t)(b * 64 + dblk * 32 + qc) * NN + kv0 + ks2 * 16 + h8];
    __builtin_amdgcn_s_setprio(1);
    f32x16 S = {};
#pragma unroll
    for (int ks = 0; ks < 4; ++ks)
      S = __builtin_amdgcn_mfma_f32_32x32x16_bf16(kf[ks], qf[ks], S, 0, 0, 0);
    __builtin_amdgcn_s_setprio(0);
    float sv[16];
    float mx = -1e30f;
    if (interior) {
      f32x4 bv[4];
#pragma unroll
      for (int g = 0; g < 4; ++g)
        bv[g] = *(const f32x4u*)(bt + (q0 + qc - kv0 - 8 * g - 4 * hid - 3));
#pragma unroll
      for (int g = 0; g < 4; ++g)
#pragma unroll
        for (int e = 0; e < 4; ++e) {
          const float val = S[g * 4 + e] + bv[g][3 - e];
          sv[g * 4 + e] = val;
          mx = fmaxf(mx, val);
        }
    } else {
#pragma unroll
      for (int r = 0; r < 16; ++r) {
        const int kvr = (r & 3) + 8 * (r >> 2) + 4 * hid;
        const int d = (q0 + qc) - (kv0 + kvr);
        const int dc = d > 0 ? d : 0;
        float val = S[r] + bt[dc];
        if (d < 0) val = -1e30f;
        sv[r] = val;
        mx = fmaxf(mx, val);
      }
    }
    if (!__all(mx <= m_run + 8.0f)) {
      mx = fmaxf(mx, __shfl_xor(mx, 32));
      const float m_new = fmaxf(m_run, mx);
      const float sc = __expf(m_run - m_new);
      l_run *= sc;
#pragma unroll
      for (int r = 0; r < 16; ++r) { Oacc0[r] *= sc; Oacc1[r] *= sc; }
      m_run = m_new;
    }
    float csum = 0.0f;
#pragma unroll
    for (int r = 0; r < 16; ++r) { sv[r] = __expf(sv[r] - m_run); csum += sv[r]; }
    csum += __shfl_xor(csum, 32);
    l_run += csum;
    int w[8];
#pragma unroll
    for (int g = 0; g < 4; ++g) {
      w[2 * g]     = pack_bf16(sv[4 * g],     sv[4 * g + 1]);
      w[2 * g + 1] = pack_bf16(sv[4 * g + 2], sv[4 * g + 3]);
    }
    bf16x8 pfrag[2];
#pragma unroll
    for (int ks2 = 0; ks2 < 2; ++ks2) {
      const int a  = w[4 * ks2],     bb = w[4 * ks2 + 1];
      const int c  = w[4 * ks2 + 2], dd = w[4 * ks2 + 3];
      const int s0 = hid ? a : c,    s1 = hid ? bb : dd;
      const int r0 = __shfl_xor(s0, 32);
      const int r1 = __shfl_xor(s1, 32);
      i32x4 fw;
      fw[0] = hid ? r0 : a;
      fw[1] = hid ? r1 : bb;
      fw[2] = hid ? c  : r0;
      fw[3] = hid ? dd : r1;
      pfrag[ks2] = __builtin_bit_cast(bf16x8, fw);
    }
    __builtin_amdgcn_s_setprio(1);
#pragma unroll
    for (int ks2 = 0; ks2 < 2; ++ks2) {
      Oacc0 = __builtin_amdgcn_mfma_f32_32x32x16_bf16(vf[0][ks2], pfrag[ks2], Oacc0, 0, 0, 0);
      Oacc1 = __builtin_amdgcn_mfma_f32_32x32x16_bf16(vf[1][ks2], pfrag[ks2], Oacc1, 0, 0, 0);
    }
    __builtin_amdgcn_s_setprio(0);
    kv0 += 32;
  }
#pragma unroll
  for (int r = 0; r < 16; ++r) {
    const int dl = (r & 3) + 8 * (r >> 2) + 4 * hid;
    prow[dl]      = Oacc0[r];
    prow[32 + dl] = Oacc1[r];
  }
  if (hid == 0)
    ((float2*)mlbuf)[(size_t)split * AROWS + Rbase + qc] = make_float2(m_run, l_run);
}

// ======================= combine split-KV partials -> O (bf16) =================
// Opart layout: [split][bh][NN q][64 d] f32 (q-major), dq-fastest thread mapping.
__global__ void attn_combine(const float* __restrict__ Opart, const float* __restrict__ mlbuf,
                             bf16* __restrict__ O) {
  const int gtid = blockIdx.x * 256 + threadIdx.x;   // NB*NH*NN*16 threads
  const int dq = gtid & 15;
  const int q  = (gtid >> 4) & (NN - 1);
  const int bh = gtid >> 15;                          // b*NH + h
  const int R = bh * NN + q;
  float2 ml[NSPLIT];
  float m = -1e30f;
#pragma unroll
  for (int s = 0; s < NSPLIT; ++s) {
    ml[s] = ((const float2*)mlbuf)[(size_t)s * AROWS + R];
    m = fmaxf(m, ml[s].x);
  }
  float w[NSPLIT];
  float denom = 0.0f;
#pragma unroll
  for (int s = 0; s < NSPLIT; ++s) {
    w[s] = __expf(ml[s].x - m);
    denom += ml[s].y * w[s];
  }
  const float inv = 1.0f / denom;
  float o[4] = {};
#pragma unroll
  for (int s = 0; s < NSPLIT; ++s) {
    const f32x4 v = *(const f32x4*)(Opart + ((size_t)(s * NB * NH + bh) * NN + q) * 64 + dq * 4);
#pragma unroll
    for (int j = 0; j < 4; ++j) o[j] += v[j] * w[s];
  }
  bf16x4 res;
#pragma unroll
  for (int j = 0; j < 4; ++j) res[j] = (bf16)(o[j] * inv);
  const int h = bh & (NH - 1), b = bh >> 3;
  *(bf16x4*)&O[(size_t)(b * NN + q) * INNER + h * DH + dq * 4] = res;
}

// ======================= launch ==========================
extern "C" void kernel_launch(void* const* d_in, const int* in_sizes, int n_in,
                              void* d_out, int out_size, void* d_ws, size_t ws_size,
                              hipStream_t stream) {
  (void)in_sizes; (void)n_in; (void)out_size;
  const float* in_x  = (const float*)d_in[0];
  const float* rel   = (const float*)d_in[1];
  const float* ln1g  = (const float*)d_in[2];
  const float* ln1b  = (const float*)d_in[3];
  const float* wq    = (const float*)d_in[4];
  const float* wkv   = (const float*)d_in[5];
  const float* wo    = (const float*)d_in[6];
  const float* ln2g  = (const float*)d_in[7];
  const float* ln2b  = (const float*)d_in[8];
  const float* w1    = (const float*)d_in[9];
  const float* w2    = (const float*)d_in[10];
  const float* lnfg  = (const float*)d_in[11];
  const float* lnfb  = (const float*)d_in[12];
  float* out = (float*)d_out;

  constexpr size_t E_QKV = (size_t)QKVN * DIM;   // fused wq|wkv, [640][1024]
  constexpr size_t E_WO  = (size_t)DIM * INNER;
  constexpr size_t E_W1F = (size_t)FF2N * DIM;   // interleaved a/g [5632][1024]
  constexpr size_t E_W2  = (size_t)DIM * FFP;
  bf16* wqkvT = (bf16*)d_ws;
  bf16* woT  = wqkvT + NLAY * E_QKV;
  bf16* w1fT = woT  + NLAY * E_WO;
  bf16* w2T  = w1fT + NLAY * E_W1F;
  bf16* xnb  = w2T  + NLAY * E_W2;
  bf16* qkvb = xnb  + (size_t)MROW * DIM;
  bf16* vTb  = qkvb + (size_t)MROW * QKVN;
  bf16* ob   = vTb  + (size_t)NB * 64 * NN;
  bf16* hb   = ob   + (size_t)MROW * INNER;      // FF phase: compact [4096][FFP]
  float* xbuf = (float*)(hb + (size_t)MROW * FF2N);
  float* btab = xbuf + (size_t)MROW * DIM;
  const size_t needed = (size_t)((char*)(btab + NH * NN) - (char*)d_ws);
  if (ws_size < needed) return;  // visible clean failure instead of corruption
  // attn partials overlaid on hb (FF phase and attn phase are disjoint in time):
  float* Opart = (float*)hb;
  float* mlbuf = (float*)(hb + (size_t)18 * 1024 * 1024);
  hipMemcpyAsync(xbuf, in_x, (size_t)MROW * DIM * sizeof(float),
                 hipMemcpyDeviceToDevice, stream);
  btab_kernel<<<8, 256, 0, stream>>>(rel, btab);

  const dim3 tb(32, 8);
  conv_tr<<<dim3(16, 32, 6), tb, 0, stream>>>(wq,  (size_t)DIM*INNER, INNER, 0, DIM, INNER,
                                              wqkvT, E_QKV, DIM, 0.125f, -1);  // fold DH^-0.5
  conv_tr<<<dim3(4, 32, 6),  tb, 0, stream>>>(wkv, (size_t)DIM*128, 128, 0, DIM, 128,
                                              wqkvT + (size_t)INNER*DIM, E_QKV, DIM, 1.0f, -1);
  conv_tr<<<dim3(32, 16, 6), tb, 0, stream>>>(wo,  (size_t)INNER*DIM, DIM, 0, INNER, DIM,
                                              woT,  E_WO, INNER, 1.0f, -1);
  conv_tr<<<dim3(88, 32, 6), tb, 0, stream>>>(w1,  (size_t)DIM*2*FF, 2*FF, 0, DIM, FF,
                                              w1fT, E_W1F, DIM, 1.0f, 0);    // a rows -> +0
  conv_tr<<<dim3(88, 32, 6), tb, 0, stream>>>(w1,  (size_t)DIM*2*FF, 2*FF, FF, DIM, FF,
                                              w1fT, E_W1F, DIM, 1.0f, 16);   // g rows -> +16
  conv_tr<<<dim3(32, 88, 6), tb, 0, stream>>>(w2,  (size_t)FF*DIM, DIM, 0, FF, DIM,
                                              w2T,  E_W2, FFP, 1.0f, -1);

  for (int l = 0; l < NLAY; ++l) {
    ln_kernel<bf16><<<MROW, 256, 0, stream>>>(xbuf, ln1g + l*DIM, ln1b + l*DIM, xnb);
    gemm_bt<0><<<dim3(QKVN/128, MROW/128), 512, 0, stream>>>(xnb, wqkvT + l*E_QKV, DIM, DIM, QKVN, qkvb, nullptr);
    vt_kernel<<<dim3(NN/32, 2, NB), tb, 0, stream>>>(qkvb, vTb);
    attn_kernel<<<dim3((NN/32)*NSPLIT, NH/4, NB), 256, 0, stream>>>(qkvb, vTb, btab, Opart, mlbuf);
    attn_combine<<<AROWS*16/256, 256, 0, stream>>>(Opart, mlbuf, ob);
    gemm_bt<3><<<dim3(DIM/128, MROW/128, 2), 512, 0, stream>>>(ob, woT + l*E_WO, INNER, INNER, DIM, nullptr, xbuf);
    ln_kernel<bf16><<<MROW, 256, 0, stream>>>(xbuf, ln2g + l*DIM, ln2b + l*DIM, xnb);
    gemm97<2><<<dim3(FF2N/128, MROW/128), 256, 0, stream>>>(xnb, w1fT + l*E_W1F, DIM, DIM, FFP, hb, nullptr);
    gemm_bt<3><<<dim3(DIM/128, MROW/128, 2), 512, 0, stream>>>(hb, w2T + l*E_W2, FFP, FFP, DIM, nullptr, xbuf);
  }
  ln_kernel<float><<<MROW, 256, 0, stream>>>(xbuf, lnfg, lnfb, out);
}

// Round 13
// 1507.555 us; speedup vs baseline: 1.1001x; 1.1001x over previous
//
#include <hip/hip_runtime.h>
#include <cstdint>
#include <cstddef>

using bf16 = __bf16;
typedef __bf16 bf16x8 __attribute__((ext_vector_type(8)));
typedef __bf16 bf16x4 __attribute__((ext_vector_type(4)));
typedef __bf16 bf16x2 __attribute__((ext_vector_type(2)));
typedef float  f32x4  __attribute__((ext_vector_type(4)));
typedef float  f32x16 __attribute__((ext_vector_type(16)));
typedef int    i32x4  __attribute__((ext_vector_type(4)));
typedef float  f32x4u __attribute__((ext_vector_type(4), aligned(4)));  // 4B-aligned vec load

// ---- problem constants ----
constexpr int NB   = 2;      // batch
constexpr int NN   = 2048;   // seq
constexpr int DIM  = 1024;
constexpr int NH   = 8;
constexpr int DH   = 64;
constexpr int INNER= 512;
constexpr int QKVN = 640;    // fused Q(512) + K(64) + V(64) projection width
constexpr int FF   = 2730;
constexpr int FFP  = 2816;   // padded FF (22*128)
constexpr int FF2N = 5632;   // fused a|g FF1 output width (interleaved 32-groups)
constexpr int MROW = NB * NN;   // 4096
constexpr int NLAY = 6;
constexpr int AROWS = NB * NH * NN;  // 32768 attention (b,h,q) rows
constexpr int NSPLIT = 4;            // KV splits

// async global->LDS, 16B per lane; LDS dest is wave-uniform base (+lane*16 by HW)
__device__ __forceinline__ void gload_lds16(const bf16* g, bf16* l) {
  __builtin_amdgcn_global_load_lds((const __attribute__((address_space(1))) void*)g,
                                   (__attribute__((address_space(3))) void*)l,
                                   16, 0, 0);
}

__device__ __forceinline__ int pack_bf16(float lo, float hi_) {
  bf16x2 t; t[0] = (bf16)lo; t[1] = (bf16)hi_;
  return __builtin_bit_cast(int, t);
}

// ======================= bias table ==========================
__global__ void btab_kernel(const float* __restrict__ rel, float* __restrict__ btab) {
  int d = blockIdx.x * 256 + threadIdx.x;
  if (d >= NN) return;
  int bucket;
  if (d < 16) bucket = d;
  else {
    int vl = 16 + (int)(logf((float)d / 16.0f) / logf(8.0f) * 16.0f);
    bucket = vl < 31 ? vl : 31;
  }
  for (int h = 0; h < NH; ++h) btab[h * NN + d] = rel[bucket * NH + h];
}

// ============== weight convert + transpose (+pad, +scale, +row-remap) ==============
// rowOff16 < 0: dst row = i.  rowOff16 >= 0: dst row = ((i>>4)<<5) + rowOff16 + (i&15)
// (interleaves two sources into 32-row groups: a rows at +0, g rows at +16).
__global__ void conv_tr(const float* __restrict__ src, size_t srcLayer, int srcStride,
                        int colOff, int R, int C,
                        bf16* __restrict__ dst, size_t dstLayer, int Tcols, float scale,
                        int rowOff16) {
  __shared__ float tile[32][33];
  const int i0 = blockIdx.x * 32, j0 = blockIdx.y * 32, z = blockIdx.z;
  const float* s = src + (size_t)z * srcLayer;
  bf16* d = dst + (size_t)z * dstLayer;
  const int tx = threadIdx.x, ty = threadIdx.y;
#pragma unroll
  for (int k = 0; k < 4; ++k) {
    int j = j0 + ty + k * 8;
    int i = i0 + tx;
    float v = 0.0f;
    if (j < R && i < C) v = s[(size_t)j * srcStride + colOff + i] * scale;
    tile[ty + k * 8][tx] = v;
  }
  __syncthreads();
#pragma unroll
  for (int k = 0; k < 4; ++k) {
    int i = i0 + ty + k * 8;   // logical dst row
    int j = j0 + tx;           // dst col
    int dr = (rowOff16 >= 0) ? (((i >> 4) << 5) + rowOff16 + (i & 15)) : i;
    d[(size_t)dr * Tcols + j] = (bf16)tile[tx][ty + k * 8];
  }
}

// ======================= LayerNorm ==========================
template <typename OUT>
__global__ void ln_kernel(const float* __restrict__ X, const float* __restrict__ G,
                          const float* __restrict__ Bt, OUT* __restrict__ out) {
  __shared__ float red[8];
  const int row = blockIdx.x, t = threadIdx.x;
  const float* xr = X + (size_t)row * DIM;
  float4 v = *(const float4*)(xr + t * 4);
  float s  = v.x + v.y + v.z + v.w;
  float s2 = v.x * v.x + v.y * v.y + v.z * v.z + v.w * v.w;
#pragma unroll
  for (int o = 1; o < 64; o <<= 1) { s += __shfl_xor(s, o); s2 += __shfl_xor(s2, o); }
  if ((t & 63) == 0) { red[t >> 6] = s; red[4 + (t >> 6)] = s2; }
  __syncthreads();
  float S  = red[0] + red[1] + red[2] + red[3];
  float S2 = red[4] + red[5] + red[6] + red[7];
  const float inv = 1.0f / (float)DIM;
  float mu = S * inv;
  float var = S2 * inv - mu * mu;
  float rstd = rsqrtf(var + 1e-5f);
  float4 g  = *(const float4*)(G + t * 4);
  float4 bb = *(const float4*)(Bt + t * 4);
  OUT* orow = out + (size_t)row * DIM + t * 4;
  orow[0] = (OUT)((v.x - mu) * rstd * g.x + bb.x);
  orow[1] = (OUT)((v.y - mu) * rstd * g.y + bb.y);
  orow[2] = (OUT)((v.z - mu) * rstd * g.z + bb.z);
  orow[3] = (OUT)((v.w - mu) * rstd * g.w + bb.w);
}

// ======================= GEMM 128x128 (r6 core; QKV) ==========================
// 128x128 tile, BK=64, 8 waves (2Mx4N, 64x32 each), double-buffered LDS (64KB),
// prefetch distance 1, 2 barriers/K-step. MODE 0: store bf16 C. MODE 1: Xr += acc.
template <int MODE>
__launch_bounds__(512)
__global__ void gemm_bt(const bf16* __restrict__ A, const bf16* __restrict__ B,
                        int K, int lda, int N, bf16* __restrict__ Cb, float* __restrict__ Xr) {
  __shared__ __align__(16) bf16 As[2][128 * 64];
  __shared__ __align__(16) bf16 Bs[2][128 * 64];
  const int tid = threadIdx.x;
  const int lane = tid & 63, wave = tid >> 6;
  const int gx = gridDim.x, gy = gridDim.y;
  const int nwg = gx * gy;
  const int orig = blockIdx.y * gx + blockIdx.x;
  const int wgid = (orig & 7) * (nwg >> 3) + (orig >> 3);  // XCD swizzle (nwg%8==0)
  const int m0 = (wgid % gy) * 128;   // M fastest within XCD chunk -> B-panel L2 reuse
  const int n0 = (wgid / gy) * 128;
  const int wm = (wave >> 2) * 64, wn = (wave & 3) * 32;
  const int fr = lane & 15, fg8 = (lane >> 4) * 8;
  const int frl8 = (fr & 7) * 8;           // read-side swizzle XOR
  const int rL = lane >> 3;                // staging row within 8-row group
  const int cS = ((lane & 7) ^ rL) * 8;    // pre-swizzled global source col
  const bf16* aB = A + (size_t)(m0 + wave * 8 + rL) * lda + cS;
  const bf16* bB = B + (size_t)(n0 + wave * 8 + rL) * K + cS;
  f32x4 acc[4][2] = {};

  auto STAGE = [&](int buf, int kt) {
#pragma unroll
    for (int r = 0; r < 2; ++r) {
      gload_lds16(aB + (size_t)(r * 64) * lda + kt, &As[buf][(r * 8 + wave) * 512]);
      gload_lds16(bB + (size_t)(r * 64) * K + kt, &Bs[buf][(r * 8 + wave) * 512]);
    }
  };

  STAGE(0, 0);
  const int nt = K >> 6;
  int cur = 0;
  for (int t = 0; t < nt; ++t) {
    asm volatile("s_waitcnt vmcnt(0)" ::: "memory");  // buf[cur] DMA (this wave) done
    __builtin_amdgcn_s_barrier();                     // all waves' DMA done
    __builtin_amdgcn_sched_barrier(0);
    if (t + 1 < nt) STAGE(cur ^ 1, (t + 1) * 64);     // in flight across the compute
#pragma unroll
    for (int kk = 0; kk < 64; kk += 32) {
      bf16x8 af[4], bfr[2];
#pragma unroll
      for (int m = 0; m < 4; ++m)
        af[m] = *(const bf16x8*)&As[cur][(wm + m * 16 + fr) * 64 + ((kk + fg8) ^ frl8)];
#pragma unroll
      for (int n = 0; n < 2; ++n)
        bfr[n] = *(const bf16x8*)&Bs[cur][(wn + n * 16 + fr) * 64 + ((kk + fg8) ^ frl8)];
#pragma unroll
      for (int m = 0; m < 4; ++m)
#pragma unroll
        for (int n = 0; n < 2; ++n)
          acc[m][n] = __builtin_amdgcn_mfma_f32_16x16x32_bf16(af[m], bfr[n], acc[m][n], 0, 0, 0);
    }
    __builtin_amdgcn_sched_barrier(0);
    __builtin_amdgcn_s_barrier();                     // cur fully read; next STAGE may overwrite
    cur ^= 1;
  }
  const int cc = lane & 15, cg = (lane >> 4) * 4;
#pragma unroll
  for (int m = 0; m < 4; ++m) {
#pragma unroll
    for (int n = 0; n < 2; ++n) {
      const int col = n0 + wn + n * 16 + cc;
#pragma unroll
      for (int r = 0; r < 4; ++r) {
        const int row = m0 + wm + m * 16 + cg + r;
        const size_t idx = (size_t)row * N + col;
        if (MODE == 0) Cb[idx] = (bf16)acc[m][n][r];
        else           Xr[idx] += acc[m][n][r];
      }
    }
  }
}

// ======================= GEMM 64x128 (same skeleton, doubled grid; WO/FF2) =========
// 64x128 tile, BK=64, 8 waves (2Mx4N, 32x32 each), double-buffered LDS (48KB ->
// 2+ blocks/CU by LDS) -- grids become 512 blocks = 2/CU, the measured regime
// where this skeleton hides its stage drain. Same swizzles, same sync structure.
// MODE 0: store bf16 C. MODE 1: Xr += acc (fp32 residual).
template <int MODE>
__launch_bounds__(512)
__global__ void gemm_bt64(const bf16* __restrict__ A, const bf16* __restrict__ B,
                          int K, int lda, int N, bf16* __restrict__ Cb, float* __restrict__ Xr) {
  __shared__ __align__(16) bf16 As[2][64 * 64];
  __shared__ __align__(16) bf16 Bs[2][128 * 64];
  const int tid = threadIdx.x;
  const int lane = tid & 63, wave = tid >> 6;
  const int gx = gridDim.x, gy = gridDim.y;
  const int nwg = gx * gy;
  const int orig = blockIdx.y * gx + blockIdx.x;
  const int wgid = (orig & 7) * (nwg >> 3) + (orig >> 3);  // XCD swizzle (nwg%8==0)
  const int m0 = (wgid % gy) * 64;    // M fastest within XCD chunk -> B-panel L2 reuse
  const int n0 = (wgid / gy) * 128;
  const int wm = (wave >> 2) * 32, wn = (wave & 3) * 32;
  const int fr = lane & 15, fg8 = (lane >> 4) * 8;
  const int frl8 = (fr & 7) * 8;           // read-side swizzle XOR
  const int rL = lane >> 3;                // staging row within 8-row group
  const int cS = ((lane & 7) ^ rL) * 8;    // pre-swizzled global source col
  const bf16* aB = A + (size_t)(m0 + wave * 8 + rL) * lda + cS;
  const bf16* bB = B + (size_t)(n0 + wave * 8 + rL) * K + cS;
  f32x4 acc[2][2] = {};

  auto STAGE = [&](int buf, int kt) {
    gload_lds16(aB + kt, &As[buf][wave * 512]);               // A: 64 rows, 1 chunk
#pragma unroll
    for (int r = 0; r < 2; ++r)                                // B: 128 rows, 2 chunks
      gload_lds16(bB + (size_t)(r * 64) * K + kt, &Bs[buf][(r * 8 + wave) * 512]);
  };

  STAGE(0, 0);
  const int nt = K >> 6;
  int cur = 0;
  for (int t = 0; t < nt; ++t) {
    asm volatile("s_waitcnt vmcnt(0)" ::: "memory");
    __builtin_amdgcn_s_barrier();
    __builtin_amdgcn_sched_barrier(0);
    if (t + 1 < nt) STAGE(cur ^ 1, (t + 1) * 64);
#pragma unroll
    for (int kk = 0; kk < 64; kk += 32) {
      bf16x8 af[2], bfr[2];
#pragma unroll
      for (int m = 0; m < 2; ++m)
        af[m] = *(const bf16x8*)&As[cur][(wm + m * 16 + fr) * 64 + ((kk + fg8) ^ frl8)];
#pragma unroll
      for (int n = 0; n < 2; ++n)
        bfr[n] = *(const bf16x8*)&Bs[cur][(wn + n * 16 + fr) * 64 + ((kk + fg8) ^ frl8)];
#pragma unroll
      for (int m = 0; m < 2; ++m)
#pragma unroll
        for (int n = 0; n < 2; ++n)
          acc[m][n] = __builtin_amdgcn_mfma_f32_16x16x32_bf16(af[m], bfr[n], acc[m][n], 0, 0, 0);
    }
    __builtin_amdgcn_sched_barrier(0);
    __builtin_amdgcn_s_barrier();
    cur ^= 1;
  }
  const int cc = lane & 15, cg = (lane >> 4) * 4;
#pragma unroll
  for (int m = 0; m < 2; ++m) {
#pragma unroll
    for (int n = 0; n < 2; ++n) {
      const int col = n0 + wn + n * 16 + cc;
#pragma unroll
      for (int r = 0; r < 4; ++r) {
        const int row = m0 + wm + m * 16 + cg + r;
        const size_t idx = (size_t)row * N + col;
        if (MODE == 0) Cb[idx] = (bf16)acc[m][n][r];
        else           Xr[idx] += acc[m][n][r];
      }
    }
  }
}

// ======================= GEMM m97-structure (for FF1: large grid) ==================
// 128x128 tile, BK=64, 4 waves (2x2, 64x64 each, 4x4 acc), SINGLE 32KB LDS buffer,
// sync/stage/sync/compute. 3-4 co-resident blocks/CU hide the stage drain.
// MODE 2: GEGLU epilogue (B rows interleaved 32-groups: a@+0..15, g@+16..31);
// writes gelu(g)*a compact with row stride N (pass N=FFP).
template <int MODE>
__launch_bounds__(256)
__global__ void gemm97(const bf16* __restrict__ A, const bf16* __restrict__ B,
                       int K, int lda, int N, bf16* __restrict__ Cb, float* __restrict__ Xr) {
  __shared__ __align__(16) bf16 As[128 * 64];
  __shared__ __align__(16) bf16 Bs[128 * 64];
  const int tid = threadIdx.x;
  const int lane = tid & 63, wave = tid >> 6;
  const int gx = gridDim.x, gy = gridDim.y;
  const int nwg = gx * gy;
  const int orig = blockIdx.y * gx + blockIdx.x;
  const int wgid = (orig & 7) * (nwg >> 3) + (orig >> 3);  // XCD swizzle (nwg%8==0)
  const int m0 = (wgid % gy) * 128;
  const int n0 = (wgid / gy) * 128;
  const int wm = (wave >> 1) * 64, wn = (wave & 1) * 64;
  const int fr = lane & 15, fg8 = (lane >> 4) * 8;
  const int frl8 = (fr & 7) * 8;
  const int rL = lane >> 3;
  const int cS = ((lane & 7) ^ rL) * 8;
  const bf16* aB = A + (size_t)(m0 + wave * 8 + rL) * lda + cS;
  const bf16* bB = B + (size_t)(n0 + wave * 8 + rL) * K + cS;
  f32x4 acc[4][4] = {};

  for (int kt = 0; kt < K; kt += 64) {
    __syncthreads();   // previous compute done reading LDS
#pragma unroll
    for (int r = 0; r < 4; ++r) {
      gload_lds16(aB + (size_t)(r * 32) * lda + kt, &As[(r * 4 + wave) * 512]);
      gload_lds16(bB + (size_t)(r * 32) * K + kt, &Bs[(r * 4 + wave) * 512]);
    }
    __syncthreads();   // drains vmcnt(0): DMA complete (compiler-inserted)
#pragma unroll
    for (int kk = 0; kk < 64; kk += 32) {
      bf16x8 af[4], bfr[4];
#pragma unroll
      for (int m = 0; m < 4; ++m)
        af[m] = *(const bf16x8*)&As[(wm + m * 16 + fr) * 64 + ((kk + fg8) ^ frl8)];
#pragma unroll
      for (int n = 0; n < 4; ++n)
        bfr[n] = *(const bf16x8*)&Bs[(wn + n * 16 + fr) * 64 + ((kk + fg8) ^ frl8)];
#pragma unroll
      for (int m = 0; m < 4; ++m)
#pragma unroll
        for (int n = 0; n < 4; ++n)
          acc[m][n] = __builtin_amdgcn_mfma_f32_16x16x32_bf16(af[m], bfr[n], acc[m][n], 0, 0, 0);
    }
  }
  const int cc = lane & 15, cg = (lane >> 4) * 4;
  if (MODE == 2) {
    const int jbase = (n0 + wn) / 2 + cc;
#pragma unroll
    for (int m = 0; m < 4; ++m) {
#pragma unroll
      for (int p = 0; p < 2; ++p) {
#pragma unroll
        for (int r = 0; r < 4; ++r) {
          const int row = m0 + wm + m * 16 + cg + r;
          const float av = acc[m][2 * p][r], gv = acc[m][2 * p + 1][r];
          const float ge = 0.5f * gv * (1.0f + erff(gv * 0.70710678118654752f)) * av;
          Cb[(size_t)row * N + jbase + p * 16] = (bf16)ge;
        }
      }
    }
  } else {
#pragma unroll
    for (int m = 0; m < 4; ++m) {
#pragma unroll
      for (int n = 0; n < 4; ++n) {
        const int col = n0 + wn + n * 16 + cc;
#pragma unroll
        for (int r = 0; r < 4; ++r) {
          const int row = m0 + wm + m * 16 + cg + r;
          const size_t idx = (size_t)row * N + col;
          if (MODE == 0) Cb[idx] = (bf16)acc[m][n][r];
          else           Xr[idx] += acc[m][n][r];
        }
      }
    }
  }
}

// ======================= V transpose: VT[b][dh][n] = QKV[b*NN+n][576+dh] ==========
__global__ void vt_kernel(const bf16* __restrict__ QKV, bf16* __restrict__ VT) {
  __shared__ bf16 t[32][33];
  const int n0 = blockIdx.x * 32, d0 = blockIdx.y * 32, b = blockIdx.z;
  const int tx = threadIdx.x, ty = threadIdx.y;
#pragma unroll
  for (int k = 0; k < 4; ++k) {
    int n = n0 + ty + k * 8;
    t[ty + k * 8][tx] = QKV[(size_t)(b * NN + n) * QKVN + 576 + d0 + tx];
  }
  __syncthreads();
#pragma unroll
  for (int k = 0; k < 4; ++k) {
    int dh = d0 + ty + k * 8;
    VT[(size_t)(b * 64 + dh) * NN + n0 + tx] = t[tx][ty + k * 8];
  }
}

// ======================= attention: 32x32 MFMA, in-register softmax ==============
// 4 waves/block = 4 heads (MQA: K/V shared -> L1 reuse), no barriers, no LDS.
// NSPLIT=4 KV splits -> 1024 blocks = 4 waves/SIMD co-resident. Partials in
// q-major layout Opart[split][bh][q][64] so combine reads are coalesced.
__launch_bounds__(256)
__global__ void attn_kernel(const bf16* __restrict__ QKV, const bf16* __restrict__ VT,
                            const float* __restrict__ btab,
                            float* __restrict__ Opart, float* __restrict__ mlbuf) {
  const int tid = threadIdx.x;
  const int lane = tid & 63, wv = tid >> 6;
  const int split = blockIdx.x & (NSPLIT - 1);
  const int qt = (NN / 32 - 1) - (blockIdx.x / NSPLIT);   // longest-first
  const int h = blockIdx.y * 4 + wv, b = blockIdx.z;
  const int q0 = qt * 32;
  const int qc = lane & 31;        // q col (also A-operand row index, also V^T d row)
  const int hid = lane >> 5;
  const int h8 = hid * 8;
  const int kv_full = q0 + 32;
  // distribute 32-row tiles among NSPLIT splits
  const int nt32 = kv_full >> 5;
  const int base = nt32 >> 2, rem = nt32 & 3;
  const int cnt = base + (split < rem ? 1 : 0);
  const int startT = split * base + (split < rem ? split : rem);
  const int lo = startT * 32;
  const int kend = lo + cnt * 32;
  const size_t obase = ((size_t)(split * NB * NH) + b * NH + h) * NN;  // q-row base
  const int Rbase = (b * NH + h) * NN + q0;
  float* prow = Opart + (obase + q0 + qc) * 64;
  if (cnt == 0) {   // empty split: zero partial block, weight 0 in combine
#pragma unroll
    for (int dd = 0; dd < 32; ++dd) prow[dd * 2 + hid] = 0.0f;
    if (hid == 0)
      ((float2*)mlbuf)[(size_t)split * AROWS + Rbase + qc] = make_float2(-1e30f, 0.0f);
    return;
  }
  const float* bt = btab + h * NN;
  bf16x8 qf[4];
#pragma unroll
  for (int ks = 0; ks < 4; ++ks)
    qf[ks] = *(const bf16x8*)&QKV[(size_t)(b * NN + q0 + qc) * QKVN + h * DH + ks * 16 + h8];

  f32x16 Oacc0 = {}, Oacc1 = {};
  float m_run = -1e30f, l_run = 0.0f;
  int kv0 = lo;

  while (kv0 < kend) {
    const bool interior = (kv0 + 32 <= q0);
    bf16x8 kf[4];
#pragma unroll
    for (int ks = 0; ks < 4; ++ks)
      kf[ks] = *(const bf16x8*)&QKV[(size_t)(b * NN + kv0 + qc) * QKVN + 512 + ks * 16 + h8];
    bf16x8 vf[2][2];
#pragma unroll
    for (int dblk = 0; dblk < 2; ++dblk)
#pragma unroll
      for (int ks2 = 0; ks2 < 2; ++ks2)
        vf[dblk][ks2] = *(const bf16x8*)&VT[(size_t)(b * 64 + dblk * 32 + qc) * NN + kv0 + ks2 * 16 + h8];
    __builtin_amdgcn_s_setprio(1);
    f32x16 S = {};
#pragma unroll
    for (int ks = 0; ks < 4; ++ks)
      S = __builtin_amdgcn_mfma_f32_32x32x16_bf16(kf[ks], qf[ks], S, 0, 0, 0);
    __builtin_amdgcn_s_setprio(0);
    float sv[16];
    float mx = -1e30f;
    if (interior) {
      f32x4 bv[4];
#pragma unroll
      for (int g = 0; g < 4; ++g)
        bv[g] = *(const f32x4u*)(bt + (q0 + qc - kv0 - 8 * g - 4 * hid - 3));
#pragma unroll
      for (int g = 0; g < 4; ++g)
#pragma unroll
        for (int e = 0; e < 4; ++e) {
          const float val = S[g * 4 + e] + bv[g][3 - e];
          sv[g * 4 + e] = val;
          mx = fmaxf(mx, val);
        }
    } else {
#pragma unroll
      for (int r = 0; r < 16; ++r) {
        const int kvr = (r & 3) + 8 * (r >> 2) + 4 * hid;
        const int d = (q0 + qc) - (kv0 + kvr);
        const int dc = d > 0 ? d : 0;
        float val = S[r] + bt[dc];
        if (d < 0) val = -1e30f;
        sv[r] = val;
        mx = fmaxf(mx, val);
      }
    }
    if (!__all(mx <= m_run + 8.0f)) {
      mx = fmaxf(mx, __shfl_xor(mx, 32));
      const float m_new = fmaxf(m_run, mx);
      const float sc = __expf(m_run - m_new);
      l_run *= sc;
#pragma unroll
      for (int r = 0; r < 16; ++r) { Oacc0[r] *= sc; Oacc1[r] *= sc; }
      m_run = m_new;
    }
    float csum = 0.0f;
#pragma unroll
    for (int r = 0; r < 16; ++r) { sv[r] = __expf(sv[r] - m_run); csum += sv[r]; }
    csum += __shfl_xor(csum, 32);
    l_run += csum;
    int w[8];
#pragma unroll
    for (int g = 0; g < 4; ++g) {
      w[2 * g]     = pack_bf16(sv[4 * g],     sv[4 * g + 1]);
      w[2 * g + 1] = pack_bf16(sv[4 * g + 2], sv[4 * g + 3]);
    }
    bf16x8 pfrag[2];
#pragma unroll
    for (int ks2 = 0; ks2 < 2; ++ks2) {
      const int a  = w[4 * ks2],     bb = w[4 * ks2 + 1];
      const int c  = w[4 * ks2 + 2], dd = w[4 * ks2 + 3];
      const int s0 = hid ? a : c,    s1 = hid ? bb : dd;
      const int r0 = __shfl_xor(s0, 32);
      const int r1 = __shfl_xor(s1, 32);
      i32x4 fw;
      fw[0] = hid ? r0 : a;
      fw[1] = hid ? r1 : bb;
      fw[2] = hid ? c  : r0;
      fw[3] = hid ? dd : r1;
      pfrag[ks2] = __builtin_bit_cast(bf16x8, fw);
    }
    __builtin_amdgcn_s_setprio(1);
#pragma unroll
    for (int ks2 = 0; ks2 < 2; ++ks2) {
      Oacc0 = __builtin_amdgcn_mfma_f32_32x32x16_bf16(vf[0][ks2], pfrag[ks2], Oacc0, 0, 0, 0);
      Oacc1 = __builtin_amdgcn_mfma_f32_32x32x16_bf16(vf[1][ks2], pfrag[ks2], Oacc1, 0, 0, 0);
    }
    __builtin_amdgcn_s_setprio(0);
    kv0 += 32;
  }
#pragma unroll
  for (int r = 0; r < 16; ++r) {
    const int dl = (r & 3) + 8 * (r >> 2) + 4 * hid;
    prow[dl]      = Oacc0[r];
    prow[32 + dl] = Oacc1[r];
  }
  if (hid == 0)
    ((float2*)mlbuf)[(size_t)split * AROWS + Rbase + qc] = make_float2(m_run, l_run);
}

// ======================= combine split-KV partials -> O (bf16) =================
// Opart layout: [split][bh][NN q][64 d] f32 (q-major), dq-fastest thread mapping.
__global__ void attn_combine(const float* __restrict__ Opart, const float* __restrict__ mlbuf,
                             bf16* __restrict__ O) {
  const int gtid = blockIdx.x * 256 + threadIdx.x;   // NB*NH*NN*16 threads
  const int dq = gtid & 15;
  const int q  = (gtid >> 4) & (NN - 1);
  const int bh = gtid >> 15;                          // b*NH + h
  const int R = bh * NN + q;
  float2 ml[NSPLIT];
  float m = -1e30f;
#pragma unroll
  for (int s = 0; s < NSPLIT; ++s) {
    ml[s] = ((const float2*)mlbuf)[(size_t)s * AROWS + R];
    m = fmaxf(m, ml[s].x);
  }
  float w[NSPLIT];
  float denom = 0.0f;
#pragma unroll
  for (int s = 0; s < NSPLIT; ++s) {
    w[s] = __expf(ml[s].x - m);
    denom += ml[s].y * w[s];
  }
  const float inv = 1.0f / denom;
  float o[4] = {};
#pragma unroll
  for (int s = 0; s < NSPLIT; ++s) {
    const f32x4 v = *(const f32x4*)(Opart + ((size_t)(s * NB * NH + bh) * NN + q) * 64 + dq * 4);
#pragma unroll
    for (int j = 0; j < 4; ++j) o[j] += v[j] * w[s];
  }
  bf16x4 res;
#pragma unroll
  for (int j = 0; j < 4; ++j) res[j] = (bf16)(o[j] * inv);
  const int h = bh & (NH - 1), b = bh >> 3;
  *(bf16x4*)&O[(size_t)(b * NN + q) * INNER + h * DH + dq * 4] = res;
}

// ======================= launch ==========================
extern "C" void kernel_launch(void* const* d_in, const int* in_sizes, int n_in,
                              void* d_out, int out_size, void* d_ws, size_t ws_size,
                              hipStream_t stream) {
  (void)in_sizes; (void)n_in; (void)out_size;
  const float* in_x  = (const float*)d_in[0];
  const float* rel   = (const float*)d_in[1];
  const float* ln1g  = (const float*)d_in[2];
  const float* ln1b  = (const float*)d_in[3];
  const float* wq    = (const float*)d_in[4];
  const float* wkv   = (const float*)d_in[5];
  const float* wo    = (const float*)d_in[6];
  const float* ln2g  = (const float*)d_in[7];
  const float* ln2b  = (const float*)d_in[8];
  const float* w1    = (const float*)d_in[9];
  const float* w2    = (const float*)d_in[10];
  const float* lnfg  = (const float*)d_in[11];
  const float* lnfb  = (const float*)d_in[12];
  float* out = (float*)d_out;

  constexpr size_t E_QKV = (size_t)QKVN * DIM;   // fused wq|wkv, [640][1024]
  constexpr size_t E_WO  = (size_t)DIM * INNER;
  constexpr size_t E_W1F = (size_t)FF2N * DIM;   // interleaved a/g [5632][1024]
  constexpr size_t E_W2  = (size_t)DIM * FFP;
  bf16* wqkvT = (bf16*)d_ws;
  bf16* woT  = wqkvT + NLAY * E_QKV;
  bf16* w1fT = woT  + NLAY * E_WO;
  bf16* w2T  = w1fT + NLAY * E_W1F;
  bf16* xnb  = w2T  + NLAY * E_W2;
  bf16* qkvb = xnb  + (size_t)MROW * DIM;
  bf16* vTb  = qkvb + (size_t)MROW * QKVN;
  bf16* ob   = vTb  + (size_t)NB * 64 * NN;
  bf16* hb   = ob   + (size_t)MROW * INNER;      // FF phase: compact [4096][FFP]
  float* xbuf = (float*)(hb + (size_t)MROW * FF2N);
  float* btab = xbuf + (size_t)MROW * DIM;
  const size_t needed = (size_t)((char*)(btab + NH * NN) - (char*)d_ws);
  if (ws_size < needed) return;  // visible clean failure instead of corruption
  // attn partials overlaid on hb (FF phase and attn phase are disjoint in time):
  float* Opart = (float*)hb;
  float* mlbuf = (float*)(hb + (size_t)18 * 1024 * 1024);
  hipMemcpyAsync(xbuf, in_x, (size_t)MROW * DIM * sizeof(float),
                 hipMemcpyDeviceToDevice, stream);
  btab_kernel<<<8, 256, 0, stream>>>(rel, btab);

  const dim3 tb(32, 8);
  conv_tr<<<dim3(16, 32, 6), tb, 0, stream>>>(wq,  (size_t)DIM*INNER, INNER, 0, DIM, INNER,
                                              wqkvT, E_QKV, DIM, 0.125f, -1);  // fold DH^-0.5
  conv_tr<<<dim3(4, 32, 6),  tb, 0, stream>>>(wkv, (size_t)DIM*128, 128, 0, DIM, 128,
                                              wqkvT + (size_t)INNER*DIM, E_QKV, DIM, 1.0f, -1);
  conv_tr<<<dim3(32, 16, 6), tb, 0, stream>>>(wo,  (size_t)INNER*DIM, DIM, 0, INNER, DIM,
                                              woT,  E_WO, INNER, 1.0f, -1);
  conv_tr<<<dim3(88, 32, 6), tb, 0, stream>>>(w1,  (size_t)DIM*2*FF, 2*FF, 0, DIM, FF,
                                              w1fT, E_W1F, DIM, 1.0f, 0);    // a rows -> +0
  conv_tr<<<dim3(88, 32, 6), tb, 0, stream>>>(w1,  (size_t)DIM*2*FF, 2*FF, FF, DIM, FF,
                                              w1fT, E_W1F, DIM, 1.0f, 16);   // g rows -> +16
  conv_tr<<<dim3(32, 88, 6), tb, 0, stream>>>(w2,  (size_t)FF*DIM, DIM, 0, FF, DIM,
                                              w2T,  E_W2, FFP, 1.0f, -1);

  for (int l = 0; l < NLAY; ++l) {
    ln_kernel<bf16><<<MROW, 256, 0, stream>>>(xbuf, ln1g + l*DIM, ln1b + l*DIM, xnb);
    gemm_bt<0><<<dim3(QKVN/128, MROW/128), 512, 0, stream>>>(xnb, wqkvT + l*E_QKV, DIM, DIM, QKVN, qkvb, nullptr);
    vt_kernel<<<dim3(NN/32, 2, NB), tb, 0, stream>>>(qkvb, vTb);
    attn_kernel<<<dim3((NN/32)*NSPLIT, NH/4, NB), 256, 0, stream>>>(qkvb, vTb, btab, Opart, mlbuf);
    attn_combine<<<AROWS*16/256, 256, 0, stream>>>(Opart, mlbuf, ob);
    gemm_bt64<1><<<dim3(DIM/128, MROW/64), 512, 0, stream>>>(ob, woT + l*E_WO, INNER, INNER, DIM, nullptr, xbuf);
    ln_kernel<bf16><<<MROW, 256, 0, stream>>>(xbuf, ln2g + l*DIM, ln2b + l*DIM, xnb);
    gemm97<2><<<dim3(FF2N/128, MROW/128), 256, 0, stream>>>(xnb, w1fT + l*E_W1F, DIM, DIM, FFP, hb, nullptr);
    gemm_bt64<1><<<dim3(DIM/128, MROW/64), 512, 0, stream>>>(hb, w2T + l*E_W2, FFP, FFP, DIM, nullptr, xbuf);
  }
  ln_kernel<float><<<MROW, 256, 0, stream>>>(xbuf, lnfg, lnfb, out);
}

// Round 14
// 1503.082 us; speedup vs baseline: 1.1034x; 1.0030x over previous
//
#include <hip/hip_runtime.h>
#include <cstdint>
#include <cstddef>

using bf16 = __bf16;
typedef __bf16 bf16x8 __attribute__((ext_vector_type(8)));
typedef __bf16 bf16x4 __attribute__((ext_vector_type(4)));
typedef __bf16 bf16x2 __attribute__((ext_vector_type(2)));
typedef float  f32x4  __attribute__((ext_vector_type(4)));
typedef float  f32x16 __attribute__((ext_vector_type(16)));
typedef int    i32x4  __attribute__((ext_vector_type(4)));
typedef float  f32x4u __attribute__((ext_vector_type(4), aligned(4)));  // 4B-aligned vec load

// ---- problem constants ----
constexpr int NB   = 2;      // batch
constexpr int NN   = 2048;   // seq
constexpr int DIM  = 1024;
constexpr int NH   = 8;
constexpr int DH   = 64;
constexpr int INNER= 512;
constexpr int QKVN = 640;    // fused Q(512) + K(64) + V(64) projection width
constexpr int FF   = 2730;
constexpr int FFP  = 2816;   // padded FF (22*128)
constexpr int FF2N = 5632;   // fused a|g FF1 output width (interleaved 32-groups)
constexpr int MROW = NB * NN;   // 4096
constexpr int NLAY = 6;
constexpr int AROWS = NB * NH * NN;  // 32768 attention (b,h,q) rows
constexpr int NSPLIT = 4;            // KV splits

// async global->LDS, 16B per lane; LDS dest is wave-uniform base (+lane*16 by HW)
__device__ __forceinline__ void gload_lds16(const bf16* g, bf16* l) {
  __builtin_amdgcn_global_load_lds((const __attribute__((address_space(1))) void*)g,
                                   (__attribute__((address_space(3))) void*)l,
                                   16, 0, 0);
}

__device__ __forceinline__ int pack_bf16(float lo, float hi_) {
  bf16x2 t; t[0] = (bf16)lo; t[1] = (bf16)hi_;
  return __builtin_bit_cast(int, t);
}

// ======================= bias table ==========================
__global__ void btab_kernel(const float* __restrict__ rel, float* __restrict__ btab) {
  int d = blockIdx.x * 256 + threadIdx.x;
  if (d >= NN) return;
  int bucket;
  if (d < 16) bucket = d;
  else {
    int vl = 16 + (int)(logf((float)d / 16.0f) / logf(8.0f) * 16.0f);
    bucket = vl < 31 ? vl : 31;
  }
  for (int h = 0; h < NH; ++h) btab[h * NN + d] = rel[bucket * NH + h];
}

// ============== weight convert + transpose (+pad, +scale, +row-remap) ==============
// rowOff16 < 0: dst row = i.  rowOff16 >= 0: dst row = ((i>>4)<<5) + rowOff16 + (i&15)
// (interleaves two sources into 32-row groups: a rows at +0, g rows at +16).
__global__ void conv_tr(const float* __restrict__ src, size_t srcLayer, int srcStride,
                        int colOff, int R, int C,
                        bf16* __restrict__ dst, size_t dstLayer, int Tcols, float scale,
                        int rowOff16) {
  __shared__ float tile[32][33];
  const int i0 = blockIdx.x * 32, j0 = blockIdx.y * 32, z = blockIdx.z;
  const float* s = src + (size_t)z * srcLayer;
  bf16* d = dst + (size_t)z * dstLayer;
  const int tx = threadIdx.x, ty = threadIdx.y;
#pragma unroll
  for (int k = 0; k < 4; ++k) {
    int j = j0 + ty + k * 8;
    int i = i0 + tx;
    float v = 0.0f;
    if (j < R && i < C) v = s[(size_t)j * srcStride + colOff + i] * scale;
    tile[ty + k * 8][tx] = v;
  }
  __syncthreads();
#pragma unroll
  for (int k = 0; k < 4; ++k) {
    int i = i0 + ty + k * 8;   // logical dst row
    int j = j0 + tx;           // dst col
    int dr = (rowOff16 >= 0) ? (((i >> 4) << 5) + rowOff16 + (i & 15)) : i;
    d[(size_t)dr * Tcols + j] = (bf16)tile[tx][ty + k * 8];
  }
}

// ======================= LayerNorm ==========================
template <typename OUT>
__global__ void ln_kernel(const float* __restrict__ X, const float* __restrict__ G,
                          const float* __restrict__ Bt, OUT* __restrict__ out) {
  __shared__ float red[8];
  const int row = blockIdx.x, t = threadIdx.x;
  const float* xr = X + (size_t)row * DIM;
  float4 v = *(const float4*)(xr + t * 4);
  float s  = v.x + v.y + v.z + v.w;
  float s2 = v.x * v.x + v.y * v.y + v.z * v.z + v.w * v.w;
#pragma unroll
  for (int o = 1; o < 64; o <<= 1) { s += __shfl_xor(s, o); s2 += __shfl_xor(s2, o); }
  if ((t & 63) == 0) { red[t >> 6] = s; red[4 + (t >> 6)] = s2; }
  __syncthreads();
  float S  = red[0] + red[1] + red[2] + red[3];
  float S2 = red[4] + red[5] + red[6] + red[7];
  const float inv = 1.0f / (float)DIM;
  float mu = S * inv;
  float var = S2 * inv - mu * mu;
  float rstd = rsqrtf(var + 1e-5f);
  float4 g  = *(const float4*)(G + t * 4);
  float4 bb = *(const float4*)(Bt + t * 4);
  OUT* orow = out + (size_t)row * DIM + t * 4;
  orow[0] = (OUT)((v.x - mu) * rstd * g.x + bb.x);
  orow[1] = (OUT)((v.y - mu) * rstd * g.y + bb.y);
  orow[2] = (OUT)((v.z - mu) * rstd * g.z + bb.z);
  orow[3] = (OUT)((v.w - mu) * rstd * g.w + bb.w);
}

// ======================= GEMM 64x128 (2 blocks/CU; QKV/WO/FF2) =====================
// 64x128 tile, BK=64, 8 waves (2Mx4N, 32x32 each), double-buffered LDS (48KB),
// prefetch distance 1, 2 barriers/K-step. Doubled grids vs 128^2 -> 2 blocks/CU,
// the measured regime where this skeleton hides its stage drain. Source-side
// swizzle + XCD block swizzle (nwg%8==0). MODE 0: store bf16 C. MODE 1: Xr += acc.
template <int MODE>
__launch_bounds__(512)
__global__ void gemm_bt64(const bf16* __restrict__ A, const bf16* __restrict__ B,
                          int K, int lda, int N, bf16* __restrict__ Cb, float* __restrict__ Xr) {
  __shared__ __align__(16) bf16 As[2][64 * 64];
  __shared__ __align__(16) bf16 Bs[2][128 * 64];
  const int tid = threadIdx.x;
  const int lane = tid & 63, wave = tid >> 6;
  const int gx = gridDim.x, gy = gridDim.y;
  const int nwg = gx * gy;
  const int orig = blockIdx.y * gx + blockIdx.x;
  const int wgid = (orig & 7) * (nwg >> 3) + (orig >> 3);  // XCD swizzle (nwg%8==0)
  const int m0 = (wgid % gy) * 64;    // M fastest within XCD chunk -> B-panel L2 reuse
  const int n0 = (wgid / gy) * 128;
  const int wm = (wave >> 2) * 32, wn = (wave & 3) * 32;
  const int fr = lane & 15, fg8 = (lane >> 4) * 8;
  const int frl8 = (fr & 7) * 8;           // read-side swizzle XOR
  const int rL = lane >> 3;                // staging row within 8-row group
  const int cS = ((lane & 7) ^ rL) * 8;    // pre-swizzled global source col
  const bf16* aB = A + (size_t)(m0 + wave * 8 + rL) * lda + cS;
  const bf16* bB = B + (size_t)(n0 + wave * 8 + rL) * K + cS;
  f32x4 acc[2][2] = {};

  auto STAGE = [&](int buf, int kt) {
    gload_lds16(aB + kt, &As[buf][wave * 512]);               // A: 64 rows, 1 chunk
#pragma unroll
    for (int r = 0; r < 2; ++r)                                // B: 128 rows, 2 chunks
      gload_lds16(bB + (size_t)(r * 64) * K + kt, &Bs[buf][(r * 8 + wave) * 512]);
  };

  STAGE(0, 0);
  const int nt = K >> 6;
  int cur = 0;
  for (int t = 0; t < nt; ++t) {
    asm volatile("s_waitcnt vmcnt(0)" ::: "memory");
    __builtin_amdgcn_s_barrier();
    __builtin_amdgcn_sched_barrier(0);
    if (t + 1 < nt) STAGE(cur ^ 1, (t + 1) * 64);
#pragma unroll
    for (int kk = 0; kk < 64; kk += 32) {
      bf16x8 af[2], bfr[2];
#pragma unroll
      for (int m = 0; m < 2; ++m)
        af[m] = *(const bf16x8*)&As[cur][(wm + m * 16 + fr) * 64 + ((kk + fg8) ^ frl8)];
#pragma unroll
      for (int n = 0; n < 2; ++n)
        bfr[n] = *(const bf16x8*)&Bs[cur][(wn + n * 16 + fr) * 64 + ((kk + fg8) ^ frl8)];
#pragma unroll
      for (int m = 0; m < 2; ++m)
#pragma unroll
        for (int n = 0; n < 2; ++n)
          acc[m][n] = __builtin_amdgcn_mfma_f32_16x16x32_bf16(af[m], bfr[n], acc[m][n], 0, 0, 0);
    }
    __builtin_amdgcn_sched_barrier(0);
    __builtin_amdgcn_s_barrier();
    cur ^= 1;
  }
  const int cc = lane & 15, cg = (lane >> 4) * 4;
#pragma unroll
  for (int m = 0; m < 2; ++m) {
#pragma unroll
    for (int n = 0; n < 2; ++n) {
      const int col = n0 + wn + n * 16 + cc;
#pragma unroll
      for (int r = 0; r < 4; ++r) {
        const int row = m0 + wm + m * 16 + cg + r;
        const size_t idx = (size_t)row * N + col;
        if (MODE == 0) Cb[idx] = (bf16)acc[m][n][r];
        else           Xr[idx] += acc[m][n][r];
      }
    }
  }
}

// ======================= GEMM m97-structure (for FF1: large grid) ==================
// 128x128 tile, BK=64, 4 waves (2x2, 64x64 each, 4x4 acc), SINGLE 32KB LDS buffer,
// sync/stage/sync/compute. 3-4 co-resident blocks/CU hide the stage drain.
// MODE 2: GEGLU epilogue (B rows interleaved 32-groups: a@+0..15, g@+16..31);
// writes gelu(g)*a compact with row stride N (pass N=FFP).
template <int MODE>
__launch_bounds__(256)
__global__ void gemm97(const bf16* __restrict__ A, const bf16* __restrict__ B,
                       int K, int lda, int N, bf16* __restrict__ Cb, float* __restrict__ Xr) {
  __shared__ __align__(16) bf16 As[128 * 64];
  __shared__ __align__(16) bf16 Bs[128 * 64];
  const int tid = threadIdx.x;
  const int lane = tid & 63, wave = tid >> 6;
  const int gx = gridDim.x, gy = gridDim.y;
  const int nwg = gx * gy;
  const int orig = blockIdx.y * gx + blockIdx.x;
  const int wgid = (orig & 7) * (nwg >> 3) + (orig >> 3);  // XCD swizzle (nwg%8==0)
  const int m0 = (wgid % gy) * 128;
  const int n0 = (wgid / gy) * 128;
  const int wm = (wave >> 1) * 64, wn = (wave & 1) * 64;
  const int fr = lane & 15, fg8 = (lane >> 4) * 8;
  const int frl8 = (fr & 7) * 8;
  const int rL = lane >> 3;
  const int cS = ((lane & 7) ^ rL) * 8;
  const bf16* aB = A + (size_t)(m0 + wave * 8 + rL) * lda + cS;
  const bf16* bB = B + (size_t)(n0 + wave * 8 + rL) * K + cS;
  f32x4 acc[4][4] = {};

  for (int kt = 0; kt < K; kt += 64) {
    __syncthreads();   // previous compute done reading LDS
#pragma unroll
    for (int r = 0; r < 4; ++r) {
      gload_lds16(aB + (size_t)(r * 32) * lda + kt, &As[(r * 4 + wave) * 512]);
      gload_lds16(bB + (size_t)(r * 32) * K + kt, &Bs[(r * 4 + wave) * 512]);
    }
    __syncthreads();   // drains vmcnt(0): DMA complete (compiler-inserted)
#pragma unroll
    for (int kk = 0; kk < 64; kk += 32) {
      bf16x8 af[4], bfr[4];
#pragma unroll
      for (int m = 0; m < 4; ++m)
        af[m] = *(const bf16x8*)&As[(wm + m * 16 + fr) * 64 + ((kk + fg8) ^ frl8)];
#pragma unroll
      for (int n = 0; n < 4; ++n)
        bfr[n] = *(const bf16x8*)&Bs[(wn + n * 16 + fr) * 64 + ((kk + fg8) ^ frl8)];
#pragma unroll
      for (int m = 0; m < 4; ++m)
#pragma unroll
        for (int n = 0; n < 4; ++n)
          acc[m][n] = __builtin_amdgcn_mfma_f32_16x16x32_bf16(af[m], bfr[n], acc[m][n], 0, 0, 0);
    }
  }
  const int cc = lane & 15, cg = (lane >> 4) * 4;
  if (MODE == 2) {
    const int jbase = (n0 + wn) / 2 + cc;
#pragma unroll
    for (int m = 0; m < 4; ++m) {
#pragma unroll
      for (int p = 0; p < 2; ++p) {
#pragma unroll
        for (int r = 0; r < 4; ++r) {
          const int row = m0 + wm + m * 16 + cg + r;
          const float av = acc[m][2 * p][r], gv = acc[m][2 * p + 1][r];
          const float ge = 0.5f * gv * (1.0f + erff(gv * 0.70710678118654752f)) * av;
          Cb[(size_t)row * N + jbase + p * 16] = (bf16)ge;
        }
      }
    }
  } else {
#pragma unroll
    for (int m = 0; m < 4; ++m) {
#pragma unroll
      for (int n = 0; n < 4; ++n) {
        const int col = n0 + wn + n * 16 + cc;
#pragma unroll
        for (int r = 0; r < 4; ++r) {
          const int row = m0 + wm + m * 16 + cg + r;
          const size_t idx = (size_t)row * N + col;
          if (MODE == 0) Cb[idx] = (bf16)acc[m][n][r];
          else           Xr[idx] += acc[m][n][r];
        }
      }
    }
  }
}

// ======================= V transpose: VT[b][dh][n] = QKV[b*NN+n][576+dh] ==========
__global__ void vt_kernel(const bf16* __restrict__ QKV, bf16* __restrict__ VT) {
  __shared__ bf16 t[32][33];
  const int n0 = blockIdx.x * 32, d0 = blockIdx.y * 32, b = blockIdx.z;
  const int tx = threadIdx.x, ty = threadIdx.y;
#pragma unroll
  for (int k = 0; k < 4; ++k) {
    int n = n0 + ty + k * 8;
    t[ty + k * 8][tx] = QKV[(size_t)(b * NN + n) * QKVN + 576 + d0 + tx];
  }
  __syncthreads();
#pragma unroll
  for (int k = 0; k < 4; ++k) {
    int dh = d0 + ty + k * 8;
    VT[(size_t)(b * 64 + dh) * NN + n0 + tx] = t[tx][ty + k * 8];
  }
}

// ======================= attention: 32x32 MFMA, in-register softmax ==============
// 4 waves/block = 4 heads (MQA: K/V shared -> L1 reuse), no barriers, no LDS.
// NSPLIT=4 KV splits -> 1024 blocks = 4 waves/SIMD. 1-deep K/V load pipeline:
// next tile's 8 fragment loads issue BEFORE current tile's QK/softmax/PV, hiding
// L2/HBM latency under ~600cy of compute (named structs, static indexing only).
// Partials q-major Opart[split][bh][q][64] for coalesced combine.
__launch_bounds__(256)
__global__ void attn_kernel(const bf16* __restrict__ QKV, const bf16* __restrict__ VT,
                            const float* __restrict__ btab,
                            float* __restrict__ Opart, float* __restrict__ mlbuf) {
  const int tid = threadIdx.x;
  const int lane = tid & 63, wv = tid >> 6;
  const int split = blockIdx.x & (NSPLIT - 1);
  const int qt = (NN / 32 - 1) - (blockIdx.x / NSPLIT);   // longest-first
  const int h = blockIdx.y * 4 + wv, b = blockIdx.z;
  const int q0 = qt * 32;
  const int qc = lane & 31;        // q col (also A-operand row index, also V^T d row)
  const int hid = lane >> 5;
  const int h8 = hid * 8;
  const int kv_full = q0 + 32;
  // distribute 32-row tiles among NSPLIT splits
  const int nt32 = kv_full >> 5;
  const int base = nt32 >> 2, rem = nt32 & 3;
  const int cnt = base + (split < rem ? 1 : 0);
  const int startT = split * base + (split < rem ? split : rem);
  const int lo = startT * 32;
  const int kend = lo + cnt * 32;
  const size_t obase = ((size_t)(split * NB * NH) + b * NH + h) * NN;  // q-row base
  const int Rbase = (b * NH + h) * NN + q0;
  float* prow = Opart + (obase + q0 + qc) * 64;
  if (cnt == 0) {   // empty split: zero partial block, weight 0 in combine
#pragma unroll
    for (int dd = 0; dd < 32; ++dd) prow[dd * 2 + hid] = 0.0f;
    if (hid == 0)
      ((float2*)mlbuf)[(size_t)split * AROWS + Rbase + qc] = make_float2(-1e30f, 0.0f);
    return;
  }
  const float* bt = btab + h * NN;
  bf16x8 qf[4];
#pragma unroll
  for (int ks = 0; ks < 4; ++ks)
    qf[ks] = *(const bf16x8*)&QKV[(size_t)(b * NN + q0 + qc) * QKVN + h * DH + ks * 16 + h8];

  struct KV { bf16x8 kf[4]; bf16x8 vf[2][2]; };
  auto LOAD = [&](KV& d, int kvt) {
#pragma unroll
    for (int ks = 0; ks < 4; ++ks)
      d.kf[ks] = *(const bf16x8*)&QKV[(size_t)(b * NN + kvt + qc) * QKVN + 512 + ks * 16 + h8];
#pragma unroll
    for (int dblk = 0; dblk < 2; ++dblk)
#pragma unroll
      for (int ks2 = 0; ks2 < 2; ++ks2)
        d.vf[dblk][ks2] = *(const bf16x8*)&VT[(size_t)(b * 64 + dblk * 32 + qc) * NN + kvt + ks2 * 16 + h8];
  };

  f32x16 Oacc0 = {}, Oacc1 = {};
  float m_run = -1e30f, l_run = 0.0f;
  int kv0 = lo;
  KV cur;
  LOAD(cur, kv0);

  while (kv0 < kend) {
    const bool more = (kv0 + 32 < kend);
    KV nxt;
    if (more) LOAD(nxt, kv0 + 32);     // in flight across this tile's compute
    const bool interior = (kv0 + 32 <= q0);
    __builtin_amdgcn_s_setprio(1);
    f32x16 S = {};
#pragma unroll
    for (int ks = 0; ks < 4; ++ks)
      S = __builtin_amdgcn_mfma_f32_32x32x16_bf16(cur.kf[ks], qf[ks], S, 0, 0, 0);
    __builtin_amdgcn_s_setprio(0);
    float sv[16];
    float mx = -1e30f;
    if (interior) {
      f32x4 bv[4];
#pragma unroll
      for (int g = 0; g < 4; ++g)
        bv[g] = *(const f32x4u*)(bt + (q0 + qc - kv0 - 8 * g - 4 * hid - 3));
#pragma unroll
      for (int g = 0; g < 4; ++g)
#pragma unroll
        for (int e = 0; e < 4; ++e) {
          const float val = S[g * 4 + e] + bv[g][3 - e];
          sv[g * 4 + e] = val;
          mx = fmaxf(mx, val);
        }
    } else {
#pragma unroll
      for (int r = 0; r < 16; ++r) {
        const int kvr = (r & 3) + 8 * (r >> 2) + 4 * hid;
        const int d = (q0 + qc) - (kv0 + kvr);
        const int dc = d > 0 ? d : 0;
        float val = S[r] + bt[dc];
        if (d < 0) val = -1e30f;
        sv[r] = val;
        mx = fmaxf(mx, val);
      }
    }
    if (!__all(mx <= m_run + 8.0f)) {
      mx = fmaxf(mx, __shfl_xor(mx, 32));
      const float m_new = fmaxf(m_run, mx);
      const float sc = __expf(m_run - m_new);
      l_run *= sc;
#pragma unroll
      for (int r = 0; r < 16; ++r) { Oacc0[r] *= sc; Oacc1[r] *= sc; }
      m_run = m_new;
    }
    float csum = 0.0f;
#pragma unroll
    for (int r = 0; r < 16; ++r) { sv[r] = __expf(sv[r] - m_run); csum += sv[r]; }
    csum += __shfl_xor(csum, 32);
    l_run += csum;
    int w[8];
#pragma unroll
    for (int g = 0; g < 4; ++g) {
      w[2 * g]     = pack_bf16(sv[4 * g],     sv[4 * g + 1]);
      w[2 * g + 1] = pack_bf16(sv[4 * g + 2], sv[4 * g + 3]);
    }
    bf16x8 pfrag[2];
#pragma unroll
    for (int ks2 = 0; ks2 < 2; ++ks2) {
      const int a  = w[4 * ks2],     bb = w[4 * ks2 + 1];
      const int c  = w[4 * ks2 + 2], dd = w[4 * ks2 + 3];
      const int s0 = hid ? a : c,    s1 = hid ? bb : dd;
      const int r0 = __shfl_xor(s0, 32);
      const int r1 = __shfl_xor(s1, 32);
      i32x4 fw;
      fw[0] = hid ? r0 : a;
      fw[1] = hid ? r1 : bb;
      fw[2] = hid ? c  : r0;
      fw[3] = hid ? dd : r1;
      pfrag[ks2] = __builtin_bit_cast(bf16x8, fw);
    }
    __builtin_amdgcn_s_setprio(1);
#pragma unroll
    for (int ks2 = 0; ks2 < 2; ++ks2) {
      Oacc0 = __builtin_amdgcn_mfma_f32_32x32x16_bf16(cur.vf[0][ks2], pfrag[ks2], Oacc0, 0, 0, 0);
      Oacc1 = __builtin_amdgcn_mfma_f32_32x32x16_bf16(cur.vf[1][ks2], pfrag[ks2], Oacc1, 0, 0, 0);
    }
    __builtin_amdgcn_s_setprio(0);
    if (more) cur = nxt;
    kv0 += 32;
  }
#pragma unroll
  for (int r = 0; r < 16; ++r) {
    const int dl = (r & 3) + 8 * (r >> 2) + 4 * hid;
    prow[dl]      = Oacc0[r];
    prow[32 + dl] = Oacc1[r];
  }
  if (hid == 0)
    ((float2*)mlbuf)[(size_t)split * AROWS + Rbase + qc] = make_float2(m_run, l_run);
}

// ======================= combine split-KV partials -> O (bf16) =================
// Opart layout: [split][bh][NN q][64 d] f32 (q-major), dq-fastest thread mapping.
__global__ void attn_combine(const float* __restrict__ Opart, const float* __restrict__ mlbuf,
                             bf16* __restrict__ O) {
  const int gtid = blockIdx.x * 256 + threadIdx.x;   // NB*NH*NN*16 threads
  const int dq = gtid & 15;
  const int q  = (gtid >> 4) & (NN - 1);
  const int bh = gtid >> 15;                          // b*NH + h
  const int R = bh * NN + q;
  float2 ml[NSPLIT];
  float m = -1e30f;
#pragma unroll
  for (int s = 0; s < NSPLIT; ++s) {
    ml[s] = ((const float2*)mlbuf)[(size_t)s * AROWS + R];
    m = fmaxf(m, ml[s].x);
  }
  float w[NSPLIT];
  float denom = 0.0f;
#pragma unroll
  for (int s = 0; s < NSPLIT; ++s) {
    w[s] = __expf(ml[s].x - m);
    denom += ml[s].y * w[s];
  }
  const float inv = 1.0f / denom;
  float o[4] = {};
#pragma unroll
  for (int s = 0; s < NSPLIT; ++s) {
    const f32x4 v = *(const f32x4*)(Opart + ((size_t)(s * NB * NH + bh) * NN + q) * 64 + dq * 4);
#pragma unroll
    for (int j = 0; j < 4; ++j) o[j] += v[j] * w[s];
  }
  bf16x4 res;
#pragma unroll
  for (int j = 0; j < 4; ++j) res[j] = (bf16)(o[j] * inv);
  const int h = bh & (NH - 1), b = bh >> 3;
  *(bf16x4*)&O[(size_t)(b * NN + q) * INNER + h * DH + dq * 4] = res;
}

// ======================= launch ==========================
extern "C" void kernel_launch(void* const* d_in, const int* in_sizes, int n_in,
                              void* d_out, int out_size, void* d_ws, size_t ws_size,
                              hipStream_t stream) {
  (void)in_sizes; (void)n_in; (void)out_size;
  const float* in_x  = (const float*)d_in[0];
  const float* rel   = (const float*)d_in[1];
  const float* ln1g  = (const float*)d_in[2];
  const float* ln1b  = (const float*)d_in[3];
  const float* wq    = (const float*)d_in[4];
  const float* wkv   = (const float*)d_in[5];
  const float* wo    = (const float*)d_in[6];
  const float* ln2g  = (const float*)d_in[7];
  const float* ln2b  = (const float*)d_in[8];
  const float* w1    = (const float*)d_in[9];
  const float* w2    = (const float*)d_in[10];
  const float* lnfg  = (const float*)d_in[11];
  const float* lnfb  = (const float*)d_in[12];
  float* out = (float*)d_out;

  constexpr size_t E_QKV = (size_t)QKVN * DIM;   // fused wq|wkv, [640][1024]
  constexpr size_t E_WO  = (size_t)DIM * INNER;
  constexpr size_t E_W1F = (size_t)FF2N * DIM;   // interleaved a/g [5632][1024]
  constexpr size_t E_W2  = (size_t)DIM * FFP;
  bf16* wqkvT = (bf16*)d_ws;
  bf16* woT  = wqkvT + NLAY * E_QKV;
  bf16* w1fT = woT  + NLAY * E_WO;
  bf16* w2T  = w1fT + NLAY * E_W1F;
  bf16* xnb  = w2T  + NLAY * E_W2;
  bf16* qkvb = xnb  + (size_t)MROW * DIM;
  bf16* vTb  = qkvb + (size_t)MROW * QKVN;
  bf16* ob   = vTb  + (size_t)NB * 64 * NN;
  bf16* hb   = ob   + (size_t)MROW * INNER;      // FF phase: compact [4096][FFP]
  float* xbuf = (float*)(hb + (size_t)MROW * FF2N);
  float* btab = xbuf + (size_t)MROW * DIM;
  const size_t needed = (size_t)((char*)(btab + NH * NN) - (char*)d_ws);
  if (ws_size < needed) return;  // visible clean failure instead of corruption
  // attn partials overlaid on hb (FF phase and attn phase are disjoint in time):
  float* Opart = (float*)hb;
  float* mlbuf = (float*)(hb + (size_t)18 * 1024 * 1024);
  hipMemcpyAsync(xbuf, in_x, (size_t)MROW * DIM * sizeof(float),
                 hipMemcpyDeviceToDevice, stream);
  btab_kernel<<<8, 256, 0, stream>>>(rel, btab);

  const dim3 tb(32, 8);
  conv_tr<<<dim3(16, 32, 6), tb, 0, stream>>>(wq,  (size_t)DIM*INNER, INNER, 0, DIM, INNER,
                                              wqkvT, E_QKV, DIM, 0.125f, -1);  // fold DH^-0.5
  conv_tr<<<dim3(4, 32, 6),  tb, 0, stream>>>(wkv, (size_t)DIM*128, 128, 0, DIM, 128,
                                              wqkvT + (size_t)INNER*DIM, E_QKV, DIM, 1.0f, -1);
  conv_tr<<<dim3(32, 16, 6), tb, 0, stream>>>(wo,  (size_t)INNER*DIM, DIM, 0, INNER, DIM,
                                              woT,  E_WO, INNER, 1.0f, -1);
  conv_tr<<<dim3(88, 32, 6), tb, 0, stream>>>(w1,  (size_t)DIM*2*FF, 2*FF, 0, DIM, FF,
                                              w1fT, E_W1F, DIM, 1.0f, 0);    // a rows -> +0
  conv_tr<<<dim3(88, 32, 6), tb, 0, stream>>>(w1,  (size_t)DIM*2*FF, 2*FF, FF, DIM, FF,
                                              w1fT, E_W1F, DIM, 1.0f, 16);   // g rows -> +16
  conv_tr<<<dim3(32, 88, 6), tb, 0, stream>>>(w2,  (size_t)FF*DIM, DIM, 0, FF, DIM,
                                              w2T,  E_W2, FFP, 1.0f, -1);

  for (int l = 0; l < NLAY; ++l) {
    ln_kernel<bf16><<<MROW, 256, 0, stream>>>(xbuf, ln1g + l*DIM, ln1b + l*DIM, xnb);
    gemm_bt64<0><<<dim3(QKVN/128, MROW/64), 512, 0, stream>>>(xnb, wqkvT + l*E_QKV, DIM, DIM, QKVN, qkvb, nullptr);
    vt_kernel<<<dim3(NN/32, 2, NB), tb, 0, stream>>>(qkvb, vTb);
    attn_kernel<<<dim3((NN/32)*NSPLIT, NH/4, NB), 256, 0, stream>>>(qkvb, vTb, btab, Opart, mlbuf);
    attn_combine<<<AROWS*16/256, 256, 0, stream>>>(Opart, mlbuf, ob);
    gemm_bt64<1><<<dim3(DIM/128, MROW/64), 512, 0, stream>>>(ob, woT + l*E_WO, INNER, INNER, DIM, nullptr, xbuf);
    ln_kernel<bf16><<<MROW, 256, 0, stream>>>(xbuf, ln2g + l*DIM, ln2b + l*DIM, xnb);
    gemm97<2><<<dim3(FF2N/128, MROW/128), 256, 0, stream>>>(xnb, w1fT + l*E_W1F, DIM, DIM, FFP, hb, nullptr);
    gemm_bt64<1><<<dim3(DIM/128, MROW/64), 512, 0, stream>>>(hb, w2T + l*E_W2, FFP, FFP, DIM, nullptr, xbuf);
  }
  ln_kernel<float><<<MROW, 256, 0, stream>>>(xbuf, lnfg, lnfb, out);
}

// Round 15
// 1477.589 us; speedup vs baseline: 1.1224x; 1.0173x over previous
//
#include <hip/hip_runtime.h>
#include <cstdint>
#include <cstddef>

using bf16 = __bf16;
typedef __bf16 bf16x8 __attribute__((ext_vector_type(8)));
typedef __bf16 bf16x4 __attribute__((ext_vector_type(4)));
typedef __bf16 bf16x2 __attribute__((ext_vector_type(2)));
typedef float  f32x4  __attribute__((ext_vector_type(4)));
typedef float  f32x16 __attribute__((ext_vector_type(16)));
typedef int    i32x4  __attribute__((ext_vector_type(4)));
typedef float  f32x4u __attribute__((ext_vector_type(4), aligned(4)));  // 4B-aligned vec load

// ---- problem constants ----
constexpr int NB   = 2;      // batch
constexpr int NN   = 2048;   // seq
constexpr int DIM  = 1024;
constexpr int NH   = 8;
constexpr int DH   = 64;
constexpr int INNER= 512;
constexpr int QKVN = 640;    // fused Q(512) + K(64) + V(64) projection width
constexpr int FF   = 2730;
constexpr int FFP  = 2816;   // padded FF (22*128)
constexpr int FF2N = 5632;   // fused a|g FF1 output width (interleaved 32-groups)
constexpr int MROW = NB * NN;   // 4096
constexpr int NLAY = 6;
constexpr int AROWS = NB * NH * NN;  // 32768 attention (b,h,q) rows
constexpr int NSPLIT = 4;            // KV splits

// async global->LDS, 16B per lane; LDS dest is wave-uniform base (+lane*16 by HW)
__device__ __forceinline__ void gload_lds16(const bf16* g, bf16* l) {
  __builtin_amdgcn_global_load_lds((const __attribute__((address_space(1))) void*)g,
                                   (__attribute__((address_space(3))) void*)l,
                                   16, 0, 0);
}

__device__ __forceinline__ int pack_bf16(float lo, float hi_) {
  bf16x2 t; t[0] = (bf16)lo; t[1] = (bf16)hi_;
  return __builtin_bit_cast(int, t);
}

// ======================= bias table ==========================
__global__ void btab_kernel(const float* __restrict__ rel, float* __restrict__ btab) {
  int d = blockIdx.x * 256 + threadIdx.x;
  if (d >= NN) return;
  int bucket;
  if (d < 16) bucket = d;
  else {
    int vl = 16 + (int)(logf((float)d / 16.0f) / logf(8.0f) * 16.0f);
    bucket = vl < 31 ? vl : 31;
  }
  for (int h = 0; h < NH; ++h) btab[h * NN + d] = rel[bucket * NH + h];
}

// ============== weight convert + transpose (+pad, +scale, +row-remap) ==============
// rowOff16 < 0: dst row = i.  rowOff16 >= 0: dst row = ((i>>4)<<5) + rowOff16 + (i&15)
// (interleaves two sources into 32-row groups: a rows at +0, g rows at +16).
__global__ void conv_tr(const float* __restrict__ src, size_t srcLayer, int srcStride,
                        int colOff, int R, int C,
                        bf16* __restrict__ dst, size_t dstLayer, int Tcols, float scale,
                        int rowOff16) {
  __shared__ float tile[32][33];
  const int i0 = blockIdx.x * 32, j0 = blockIdx.y * 32, z = blockIdx.z;
  const float* s = src + (size_t)z * srcLayer;
  bf16* d = dst + (size_t)z * dstLayer;
  const int tx = threadIdx.x, ty = threadIdx.y;
#pragma unroll
  for (int k = 0; k < 4; ++k) {
    int j = j0 + ty + k * 8;
    int i = i0 + tx;
    float v = 0.0f;
    if (j < R && i < C) v = s[(size_t)j * srcStride + colOff + i] * scale;
    tile[ty + k * 8][tx] = v;
  }
  __syncthreads();
#pragma unroll
  for (int k = 0; k < 4; ++k) {
    int i = i0 + ty + k * 8;   // logical dst row
    int j = j0 + tx;           // dst col
    int dr = (rowOff16 >= 0) ? (((i >> 4) << 5) + rowOff16 + (i & 15)) : i;
    d[(size_t)dr * Tcols + j] = (bf16)tile[tx][ty + k * 8];
  }
}

// ======================= LayerNorm ==========================
template <typename OUT>
__global__ void ln_kernel(const float* __restrict__ X, const float* __restrict__ G,
                          const float* __restrict__ Bt, OUT* __restrict__ out) {
  __shared__ float red[8];
  const int row = blockIdx.x, t = threadIdx.x;
  const float* xr = X + (size_t)row * DIM;
  float4 v = *(const float4*)(xr + t * 4);
  float s  = v.x + v.y + v.z + v.w;
  float s2 = v.x * v.x + v.y * v.y + v.z * v.z + v.w * v.w;
#pragma unroll
  for (int o = 1; o < 64; o <<= 1) { s += __shfl_xor(s, o); s2 += __shfl_xor(s2, o); }
  if ((t & 63) == 0) { red[t >> 6] = s; red[4 + (t >> 6)] = s2; }
  __syncthreads();
  float S  = red[0] + red[1] + red[2] + red[3];
  float S2 = red[4] + red[5] + red[6] + red[7];
  const float inv = 1.0f / (float)DIM;
  float mu = S * inv;
  float var = S2 * inv - mu * mu;
  float rstd = rsqrtf(var + 1e-5f);
  float4 g  = *(const float4*)(G + t * 4);
  float4 bb = *(const float4*)(Bt + t * 4);
  OUT* orow = out + (size_t)row * DIM + t * 4;
  orow[0] = (OUT)((v.x - mu) * rstd * g.x + bb.x);
  orow[1] = (OUT)((v.y - mu) * rstd * g.y + bb.y);
  orow[2] = (OUT)((v.z - mu) * rstd * g.z + bb.z);
  orow[3] = (OUT)((v.w - mu) * rstd * g.w + bb.w);
}

// ======================= GEMM 64x128 (2 blocks/CU; QKV/WO/FF2) =====================
// 64x128 tile, BK=64, 8 waves (2Mx4N, 32x32 each), double-buffered LDS (48KB),
// prefetch distance 1, 2 barriers/K-step. Doubled grids vs 128^2 -> 2 blocks/CU.
// Source-side swizzle + XCD block swizzle (nwg%8==0).
// MODE 0: store bf16 C. MODE 1: Xr += acc (fp32 residual).
// MODE 4: store bf16 C AND for cols>=576 also write V^T (VT=(bf16*)Xr):
//         VT[(b*64 + col-576)*NN + row], rows r=0..3 contiguous -> one bf16x4 store.
template <int MODE>
__launch_bounds__(512)
__global__ void gemm_bt64(const bf16* __restrict__ A, const bf16* __restrict__ B,
                          int K, int lda, int N, bf16* __restrict__ Cb, float* __restrict__ Xr) {
  __shared__ __align__(16) bf16 As[2][64 * 64];
  __shared__ __align__(16) bf16 Bs[2][128 * 64];
  const int tid = threadIdx.x;
  const int lane = tid & 63, wave = tid >> 6;
  const int gx = gridDim.x, gy = gridDim.y;
  const int nwg = gx * gy;
  const int orig = blockIdx.y * gx + blockIdx.x;
  const int wgid = (orig & 7) * (nwg >> 3) + (orig >> 3);  // XCD swizzle (nwg%8==0)
  const int m0 = (wgid % gy) * 64;    // M fastest within XCD chunk -> B-panel L2 reuse
  const int n0 = (wgid / gy) * 128;
  const int wm = (wave >> 2) * 32, wn = (wave & 3) * 32;
  const int fr = lane & 15, fg8 = (lane >> 4) * 8;
  const int frl8 = (fr & 7) * 8;           // read-side swizzle XOR
  const int rL = lane >> 3;                // staging row within 8-row group
  const int cS = ((lane & 7) ^ rL) * 8;    // pre-swizzled global source col
  const bf16* aB = A + (size_t)(m0 + wave * 8 + rL) * lda + cS;
  const bf16* bB = B + (size_t)(n0 + wave * 8 + rL) * K + cS;
  f32x4 acc[2][2] = {};

  auto STAGE = [&](int buf, int kt) {
    gload_lds16(aB + kt, &As[buf][wave * 512]);               // A: 64 rows, 1 chunk
#pragma unroll
    for (int r = 0; r < 2; ++r)                                // B: 128 rows, 2 chunks
      gload_lds16(bB + (size_t)(r * 64) * K + kt, &Bs[buf][(r * 8 + wave) * 512]);
  };

  STAGE(0, 0);
  const int nt = K >> 6;
  int cur = 0;
  for (int t = 0; t < nt; ++t) {
    asm volatile("s_waitcnt vmcnt(0)" ::: "memory");
    __builtin_amdgcn_s_barrier();
    __builtin_amdgcn_sched_barrier(0);
    if (t + 1 < nt) STAGE(cur ^ 1, (t + 1) * 64);
#pragma unroll
    for (int kk = 0; kk < 64; kk += 32) {
      bf16x8 af[2], bfr[2];
#pragma unroll
      for (int m = 0; m < 2; ++m)
        af[m] = *(const bf16x8*)&As[cur][(wm + m * 16 + fr) * 64 + ((kk + fg8) ^ frl8)];
#pragma unroll
      for (int n = 0; n < 2; ++n)
        bfr[n] = *(const bf16x8*)&Bs[cur][(wn + n * 16 + fr) * 64 + ((kk + fg8) ^ frl8)];
#pragma unroll
      for (int m = 0; m < 2; ++m)
#pragma unroll
        for (int n = 0; n < 2; ++n)
          acc[m][n] = __builtin_amdgcn_mfma_f32_16x16x32_bf16(af[m], bfr[n], acc[m][n], 0, 0, 0);
    }
    __builtin_amdgcn_sched_barrier(0);
    __builtin_amdgcn_s_barrier();
    cur ^= 1;
  }
  const int cc = lane & 15, cg = (lane >> 4) * 4;
#pragma unroll
  for (int m = 0; m < 2; ++m) {
#pragma unroll
    for (int n = 0; n < 2; ++n) {
      const int col = n0 + wn + n * 16 + cc;
      const int row0 = m0 + wm + m * 16 + cg;
#pragma unroll
      for (int r = 0; r < 4; ++r) {
        const size_t idx = (size_t)(row0 + r) * N + col;
        if (MODE == 0 || MODE == 4) Cb[idx] = (bf16)acc[m][n][r];
        else                        Xr[idx] += acc[m][n][r];
      }
      if (MODE == 4 && col >= 576) {   // V^T side-write (rows contiguous in VT)
        bf16* VT = (bf16*)Xr;
        const int bb2 = row0 >> 11;           // batch (NN=2048)
        const int nn2 = row0 & (NN - 1);
        bf16x4 v4;
#pragma unroll
        for (int r = 0; r < 4; ++r) v4[r] = (bf16)acc[m][n][r];
        *(bf16x4*)&VT[((size_t)(bb2 * 64 + (col - 576))) * NN + nn2] = v4;
      }
    }
  }
}

// ======================= GEMM m97-structure (for FF1: large grid) ==================
// 128x128 tile, BK=64, 4 waves (2x2, 64x64 each, 4x4 acc), SINGLE 32KB LDS buffer,
// sync/stage/sync/compute. 3-4 co-resident blocks/CU hide the stage drain.
// MODE 2: GEGLU epilogue (B rows interleaved 32-groups: a@+0..15, g@+16..31);
// writes gelu(g)*a compact with row stride N (pass N=FFP).
template <int MODE>
__launch_bounds__(256)
__global__ void gemm97(const bf16* __restrict__ A, const bf16* __restrict__ B,
                       int K, int lda, int N, bf16* __restrict__ Cb, float* __restrict__ Xr) {
  __shared__ __align__(16) bf16 As[128 * 64];
  __shared__ __align__(16) bf16 Bs[128 * 64];
  const int tid = threadIdx.x;
  const int lane = tid & 63, wave = tid >> 6;
  const int gx = gridDim.x, gy = gridDim.y;
  const int nwg = gx * gy;
  const int orig = blockIdx.y * gx + blockIdx.x;
  const int wgid = (orig & 7) * (nwg >> 3) + (orig >> 3);  // XCD swizzle (nwg%8==0)
  const int m0 = (wgid % gy) * 128;
  const int n0 = (wgid / gy) * 128;
  const int wm = (wave >> 1) * 64, wn = (wave & 1) * 64;
  const int fr = lane & 15, fg8 = (lane >> 4) * 8;
  const int frl8 = (fr & 7) * 8;
  const int rL = lane >> 3;
  const int cS = ((lane & 7) ^ rL) * 8;
  const bf16* aB = A + (size_t)(m0 + wave * 8 + rL) * lda + cS;
  const bf16* bB = B + (size_t)(n0 + wave * 8 + rL) * K + cS;
  f32x4 acc[4][4] = {};

  for (int kt = 0; kt < K; kt += 64) {
    __syncthreads();   // previous compute done reading LDS
#pragma unroll
    for (int r = 0; r < 4; ++r) {
      gload_lds16(aB + (size_t)(r * 32) * lda + kt, &As[(r * 4 + wave) * 512]);
      gload_lds16(bB + (size_t)(r * 32) * K + kt, &Bs[(r * 4 + wave) * 512]);
    }
    __syncthreads();   // drains vmcnt(0): DMA complete (compiler-inserted)
#pragma unroll
    for (int kk = 0; kk < 64; kk += 32) {
      bf16x8 af[4], bfr[4];
#pragma unroll
      for (int m = 0; m < 4; ++m)
        af[m] = *(const bf16x8*)&As[(wm + m * 16 + fr) * 64 + ((kk + fg8) ^ frl8)];
#pragma unroll
      for (int n = 0; n < 4; ++n)
        bfr[n] = *(const bf16x8*)&Bs[(wn + n * 16 + fr) * 64 + ((kk + fg8) ^ frl8)];
#pragma unroll
      for (int m = 0; m < 4; ++m)
#pragma unroll
        for (int n = 0; n < 4; ++n)
          acc[m][n] = __builtin_amdgcn_mfma_f32_16x16x32_bf16(af[m], bfr[n], acc[m][n], 0, 0, 0);
    }
  }
  const int cc = lane & 15, cg = (lane >> 4) * 4;
  if (MODE == 2) {
    const int jbase = (n0 + wn) / 2 + cc;
#pragma unroll
    for (int m = 0; m < 4; ++m) {
#pragma unroll
      for (int p = 0; p < 2; ++p) {
#pragma unroll
        for (int r = 0; r < 4; ++r) {
          const int row = m0 + wm + m * 16 + cg + r;
          const float av = acc[m][2 * p][r], gv = acc[m][2 * p + 1][r];
          const float ge = 0.5f * gv * (1.0f + erff(gv * 0.70710678118654752f)) * av;
          Cb[(size_t)row * N + jbase + p * 16] = (bf16)ge;
        }
      }
    }
  } else {
#pragma unroll
    for (int m = 0; m < 4; ++m) {
#pragma unroll
      for (int n = 0; n < 4; ++n) {
        const int col = n0 + wn + n * 16 + cc;
#pragma unroll
        for (int r = 0; r < 4; ++r) {
          const int row = m0 + wm + m * 16 + cg + r;
          const size_t idx = (size_t)row * N + col;
          if (MODE == 0) Cb[idx] = (bf16)acc[m][n][r];
          else           Xr[idx] += acc[m][n][r];
        }
      }
    }
  }
}

// ======================= attention: 32x32 MFMA, in-register softmax ==============
// r13 version (no reg pipeline: VGPR ~84 -> 6 waves/SIMD; the 1-deep pipeline
// raised VGPR to ~116 -> 4 waves/SIMD and was a net ~20us regression).
// 4 waves/block = 4 heads (MQA: K/V shared -> L1 reuse), no barriers, no LDS.
// NSPLIT=4 KV splits -> 1024 blocks. Partials q-major Opart[split][bh][q][64].
__launch_bounds__(256)
__global__ void attn_kernel(const bf16* __restrict__ QKV, const bf16* __restrict__ VT,
                            const float* __restrict__ btab,
                            float* __restrict__ Opart, float* __restrict__ mlbuf) {
  const int tid = threadIdx.x;
  const int lane = tid & 63, wv = tid >> 6;
  const int split = blockIdx.x & (NSPLIT - 1);
  const int qt = (NN / 32 - 1) - (blockIdx.x / NSPLIT);   // longest-first
  const int h = blockIdx.y * 4 + wv, b = blockIdx.z;
  const int q0 = qt * 32;
  const int qc = lane & 31;        // q col (also A-operand row index, also V^T d row)
  const int hid = lane >> 5;
  const int h8 = hid * 8;
  const int kv_full = q0 + 32;
  // distribute 32-row tiles among NSPLIT splits
  const int nt32 = kv_full >> 5;
  const int base = nt32 >> 2, rem = nt32 & 3;
  const int cnt = base + (split < rem ? 1 : 0);
  const int startT = split * base + (split < rem ? split : rem);
  const int lo = startT * 32;
  const int kend = lo + cnt * 32;
  const size_t obase = ((size_t)(split * NB * NH) + b * NH + h) * NN;  // q-row base
  const int Rbase = (b * NH + h) * NN + q0;
  float* prow = Opart + (obase + q0 + qc) * 64;
  if (cnt == 0) {   // empty split: zero partial block, weight 0 in combine
#pragma unroll
    for (int dd = 0; dd < 32; ++dd) prow[dd * 2 + hid] = 0.0f;
    if (hid == 0)
      ((float2*)mlbuf)[(size_t)split * AROWS + Rbase + qc] = make_float2(-1e30f, 0.0f);
    return;
  }
  const float* bt = btab + h * NN;
  bf16x8 qf[4];
#pragma unroll
  for (int ks = 0; ks < 4; ++ks)
    qf[ks] = *(const bf16x8*)&QKV[(size_t)(b * NN + q0 + qc) * QKVN + h * DH + ks * 16 + h8];

  f32x16 Oacc0 = {}, Oacc1 = {};
  float m_run = -1e30f, l_run = 0.0f;
  int kv0 = lo;

  while (kv0 < kend) {
    const bool interior = (kv0 + 32 <= q0);
    bf16x8 kf[4];
#pragma unroll
    for (int ks = 0; ks < 4; ++ks)
      kf[ks] = *(const bf16x8*)&QKV[(size_t)(b * NN + kv0 + qc) * QKVN + 512 + ks * 16 + h8];
    bf16x8 vf[2][2];
#pragma unroll
    for (int dblk = 0; dblk < 2; ++dblk)
#pragma unroll
      for (int ks2 = 0; ks2 < 2; ++ks2)
        vf[dblk][ks2] = *(const bf16x8*)&VT[(size_t)(b * 64 + dblk * 32 + qc) * NN + kv0 + ks2 * 16 + h8];
    __builtin_amdgcn_s_setprio(1);
    f32x16 S = {};
#pragma unroll
    for (int ks = 0; ks < 4; ++ks)
      S = __builtin_amdgcn_mfma_f32_32x32x16_bf16(kf[ks], qf[ks], S, 0, 0, 0);
    __builtin_amdgcn_s_setprio(0);
    float sv[16];
    float mx = -1e30f;
    if (interior) {
      f32x4 bv[4];
#pragma unroll
      for (int g = 0; g < 4; ++g)
        bv[g] = *(const f32x4u*)(bt + (q0 + qc - kv0 - 8 * g - 4 * hid - 3));
#pragma unroll
      for (int g = 0; g < 4; ++g)
#pragma unroll
        for (int e = 0; e < 4; ++e) {
          const float val = S[g * 4 + e] + bv[g][3 - e];
          sv[g * 4 + e] = val;
          mx = fmaxf(mx, val);
        }
    } else {
#pragma unroll
      for (int r = 0; r < 16; ++r) {
        const int kvr = (r & 3) + 8 * (r >> 2) + 4 * hid;
        const int d = (q0 + qc) - (kv0 + kvr);
        const int dc = d > 0 ? d : 0;
        float val = S[r] + bt[dc];
        if (d < 0) val = -1e30f;
        sv[r] = val;
        mx = fmaxf(mx, val);
      }
    }
    if (!__all(mx <= m_run + 8.0f)) {
      mx = fmaxf(mx, __shfl_xor(mx, 32));
      const float m_new = fmaxf(m_run, mx);
      const float sc = __expf(m_run - m_new);
      l_run *= sc;
#pragma unroll
      for (int r = 0; r < 16; ++r) { Oacc0[r] *= sc; Oacc1[r] *= sc; }
      m_run = m_new;
    }
    float csum = 0.0f;
#pragma unroll
    for (int r = 0; r < 16; ++r) { sv[r] = __expf(sv[r] - m_run); csum += sv[r]; }
    csum += __shfl_xor(csum, 32);
    l_run += csum;
    int w[8];
#pragma unroll
    for (int g = 0; g < 4; ++g) {
      w[2 * g]     = pack_bf16(sv[4 * g],     sv[4 * g + 1]);
      w[2 * g + 1] = pack_bf16(sv[4 * g + 2], sv[4 * g + 3]);
    }
    bf16x8 pfrag[2];
#pragma unroll
    for (int ks2 = 0; ks2 < 2; ++ks2) {
      const int a  = w[4 * ks2],     bb = w[4 * ks2 + 1];
      const int c  = w[4 * ks2 + 2], dd = w[4 * ks2 + 3];
      const int s0 = hid ? a : c,    s1 = hid ? bb : dd;
      const int r0 = __shfl_xor(s0, 32);
      const int r1 = __shfl_xor(s1, 32);
      i32x4 fw;
      fw[0] = hid ? r0 : a;
      fw[1] = hid ? r1 : bb;
      fw[2] = hid ? c  : r0;
      fw[3] = hid ? dd : r1;
      pfrag[ks2] = __builtin_bit_cast(bf16x8, fw);
    }
    __builtin_amdgcn_s_setprio(1);
#pragma unroll
    for (int ks2 = 0; ks2 < 2; ++ks2) {
      Oacc0 = __builtin_amdgcn_mfma_f32_32x32x16_bf16(vf[0][ks2], pfrag[ks2], Oacc0, 0, 0, 0);
      Oacc1 = __builtin_amdgcn_mfma_f32_32x32x16_bf16(vf[1][ks2], pfrag[ks2], Oacc1, 0, 0, 0);
    }
    __builtin_amdgcn_s_setprio(0);
    kv0 += 32;
  }
#pragma unroll
  for (int r = 0; r < 16; ++r) {
    const int dl = (r & 3) + 8 * (r >> 2) + 4 * hid;
    prow[dl]      = Oacc0[r];
    prow[32 + dl] = Oacc1[r];
  }
  if (hid == 0)
    ((float2*)mlbuf)[(size_t)split * AROWS + Rbase + qc] = make_float2(m_run, l_run);
}

// ======================= combine split-KV partials -> O (bf16) =================
// Opart layout: [split][bh][NN q][64 d] f32 (q-major), dq-fastest thread mapping.
__global__ void attn_combine(const float* __restrict__ Opart, const float* __restrict__ mlbuf,
                             bf16* __restrict__ O) {
  const int gtid = blockIdx.x * 256 + threadIdx.x;   // NB*NH*NN*16 threads
  const int dq = gtid & 15;
  const int q  = (gtid >> 4) & (NN - 1);
  const int bh = gtid >> 15;                          // b*NH + h
  const int R = bh * NN + q;
  float2 ml[NSPLIT];
  float m = -1e30f;
#pragma unroll
  for (int s = 0; s < NSPLIT; ++s) {
    ml[s] = ((const float2*)mlbuf)[(size_t)s * AROWS + R];
    m = fmaxf(m, ml[s].x);
  }
  float w[NSPLIT];
  float denom = 0.0f;
#pragma unroll
  for (int s = 0; s < NSPLIT; ++s) {
    w[s] = __expf(ml[s].x - m);
    denom += ml[s].y * w[s];
  }
  const float inv = 1.0f / denom;
  float o[4] = {};
#pragma unroll
  for (int s = 0; s < NSPLIT; ++s) {
    const f32x4 v = *(const f32x4*)(Opart + ((size_t)(s * NB * NH + bh) * NN + q) * 64 + dq * 4);
#pragma unroll
    for (int j = 0; j < 4; ++j) o[j] += v[j] * w[s];
  }
  bf16x4 res;
#pragma unroll
  for (int j = 0; j < 4; ++j) res[j] = (bf16)(o[j] * inv);
  const int h = bh & (NH - 1), b = bh >> 3;
  *(bf16x4*)&O[(size_t)(b * NN + q) * INNER + h * DH + dq * 4] = res;
}

// ======================= launch ==========================
extern "C" void kernel_launch(void* const* d_in, const int* in_sizes, int n_in,
                              void* d_out, int out_size, void* d_ws, size_t ws_size,
                              hipStream_t stream) {
  (void)in_sizes; (void)n_in; (void)out_size;
  const float* in_x  = (const float*)d_in[0];
  const float* rel   = (const float*)d_in[1];
  const float* ln1g  = (const float*)d_in[2];
  const float* ln1b  = (const float*)d_in[3];
  const float* wq    = (const float*)d_in[4];
  const float* wkv   = (const float*)d_in[5];
  const float* wo    = (const float*)d_in[6];
  const float* ln2g  = (const float*)d_in[7];
  const float* ln2b  = (const float*)d_in[8];
  const float* w1    = (const float*)d_in[9];
  const float* w2    = (const float*)d_in[10];
  const float* lnfg  = (const float*)d_in[11];
  const float* lnfb  = (const float*)d_in[12];
  float* out = (float*)d_out;

  constexpr size_t E_QKV = (size_t)QKVN * DIM;   // fused wq|wkv, [640][1024]
  constexpr size_t E_WO  = (size_t)DIM * INNER;
  constexpr size_t E_W1F = (size_t)FF2N * DIM;   // interleaved a/g [5632][1024]
  constexpr size_t E_W2  = (size_t)DIM * FFP;
  bf16* wqkvT = (bf16*)d_ws;
  bf16* woT  = wqkvT + NLAY * E_QKV;
  bf16* w1fT = woT  + NLAY * E_WO;
  bf16* w2T  = w1fT + NLAY * E_W1F;
  bf16* xnb  = w2T  + NLAY * E_W2;
  bf16* qkvb = xnb  + (size_t)MROW * DIM;
  bf16* vTb  = qkvb + (size_t)MROW * QKVN;
  bf16* ob   = vTb  + (size_t)NB * 64 * NN;
  bf16* hb   = ob   + (size_t)MROW * INNER;      // FF phase: compact [4096][FFP]
  float* xbuf = (float*)(hb + (size_t)MROW * FF2N);
  float* btab = xbuf + (size_t)MROW * DIM;
  const size_t needed = (size_t)((char*)(btab + NH * NN) - (char*)d_ws);
  if (ws_size < needed) return;  // visible clean failure instead of corruption
  // attn partials overlaid on hb (FF phase and attn phase are disjoint in time):
  float* Opart = (float*)hb;
  float* mlbuf = (float*)(hb + (size_t)18 * 1024 * 1024);
  hipMemcpyAsync(xbuf, in_x, (size_t)MROW * DIM * sizeof(float),
                 hipMemcpyDeviceToDevice, stream);
  btab_kernel<<<8, 256, 0, stream>>>(rel, btab);

  const dim3 tb(32, 8);
  conv_tr<<<dim3(16, 32, 6), tb, 0, stream>>>(wq,  (size_t)DIM*INNER, INNER, 0, DIM, INNER,
                                              wqkvT, E_QKV, DIM, 0.125f, -1);  // fold DH^-0.5
  conv_tr<<<dim3(4, 32, 6),  tb, 0, stream>>>(wkv, (size_t)DIM*128, 128, 0, DIM, 128,
                                              wqkvT + (size_t)INNER*DIM, E_QKV, DIM, 1.0f, -1);
  conv_tr<<<dim3(32, 16, 6), tb, 0, stream>>>(wo,  (size_t)INNER*DIM, DIM, 0, INNER, DIM,
                                              woT,  E_WO, INNER, 1.0f, -1);
  conv_tr<<<dim3(88, 32, 6), tb, 0, stream>>>(w1,  (size_t)DIM*2*FF, 2*FF, 0, DIM, FF,
                                              w1fT, E_W1F, DIM, 1.0f, 0);    // a rows -> +0
  conv_tr<<<dim3(88, 32, 6), tb, 0, stream>>>(w1,  (size_t)DIM*2*FF, 2*FF, FF, DIM, FF,
                                              w1fT, E_W1F, DIM, 1.0f, 16);   // g rows -> +16
  conv_tr<<<dim3(32, 88, 6), tb, 0, stream>>>(w2,  (size_t)FF*DIM, DIM, 0, FF, DIM,
                                              w2T,  E_W2, FFP, 1.0f, -1);

  for (int l = 0; l < NLAY; ++l) {
    ln_kernel<bf16><<<MROW, 256, 0, stream>>>(xbuf, ln1g + l*DIM, ln1b + l*DIM, xnb);
    gemm_bt64<4><<<dim3(QKVN/128, MROW/64), 512, 0, stream>>>(xnb, wqkvT + l*E_QKV, DIM, DIM, QKVN, qkvb, (float*)vTb);
    attn_kernel<<<dim3((NN/32)*NSPLIT, NH/4, NB), 256, 0, stream>>>(qkvb, vTb, btab, Opart, mlbuf);
    attn_combine<<<AROWS*16/256, 256, 0, stream>>>(Opart, mlbuf, ob);
    gemm_bt64<1><<<dim3(DIM/128, MROW/64), 512, 0, stream>>>(ob, woT + l*E_WO, INNER, INNER, DIM, nullptr, xbuf);
    ln_kernel<bf16><<<MROW, 256, 0, stream>>>(xbuf, ln2g + l*DIM, ln2b + l*DIM, xnb);
    gemm97<2><<<dim3(FF2N/128, MROW/128), 256, 0, stream>>>(xnb, w1fT + l*E_W1F, DIM, DIM, FFP, hb, nullptr);
    gemm_bt64<1><<<dim3(DIM/128, MROW/64), 512, 0, stream>>>(hb, w2T + l*E_W2, FFP, FFP, DIM, nullptr, xbuf);
  }
  ln_kernel<float><<<MROW, 256, 0, stream>>>(xbuf, lnfg, lnfb, out);
}

// Round 16
// 1461.497 us; speedup vs baseline: 1.1348x; 1.0110x over previous
//
#include <hip/hip_runtime.h>
#include <cstdint>
#include <cstddef>

using bf16 = __bf16;
typedef __bf16 bf16x8 __attribute__((ext_vector_type(8)));
typedef __bf16 bf16x4 __attribute__((ext_vector_type(4)));
typedef __bf16 bf16x2 __attribute__((ext_vector_type(2)));
typedef float  f32x4  __attribute__((ext_vector_type(4)));
typedef float  f32x16 __attribute__((ext_vector_type(16)));
typedef int    i32x4  __attribute__((ext_vector_type(4)));
typedef float  f32x4u __attribute__((ext_vector_type(4), aligned(4)));  // 4B-aligned vec load

// ---- problem constants ----
constexpr int NB   = 2;      // batch
constexpr int NN   = 2048;   // seq
constexpr int DIM  = 1024;
constexpr int NH   = 8;
constexpr int DH   = 64;
constexpr int INNER= 512;
constexpr int QKVN = 640;    // fused Q(512) + K(64) + V(64) projection width
constexpr int FF   = 2730;
constexpr int FFP  = 2816;   // padded FF (22*128)
constexpr int FF2N = 5632;   // fused a|g FF1 output width (interleaved 32-groups)
constexpr int MROW = NB * NN;   // 4096
constexpr int NLAY = 6;
constexpr int AROWS = NB * NH * NN;  // 32768 attention (b,h,q) rows
constexpr int NSPLIT = 4;            // KV splits

// async global->LDS, 16B per lane; LDS dest is wave-uniform base (+lane*16 by HW)
__device__ __forceinline__ void gload_lds16(const bf16* g, bf16* l) {
  __builtin_amdgcn_global_load_lds((const __attribute__((address_space(1))) void*)g,
                                   (__attribute__((address_space(3))) void*)l,
                                   16, 0, 0);
}

__device__ __forceinline__ int pack_bf16(float lo, float hi_) {
  bf16x2 t; t[0] = (bf16)lo; t[1] = (bf16)hi_;
  return __builtin_bit_cast(int, t);
}

// ======================= bias table ==========================
__global__ void btab_kernel(const float* __restrict__ rel, float* __restrict__ btab) {
  int d = blockIdx.x * 256 + threadIdx.x;
  if (d >= NN) return;
  int bucket;
  if (d < 16) bucket = d;
  else {
    int vl = 16 + (int)(logf((float)d / 16.0f) / logf(8.0f) * 16.0f);
    bucket = vl < 31 ? vl : 31;
  }
  for (int h = 0; h < NH; ++h) btab[h * NN + d] = rel[bucket * NH + h];
}

// ============== weight convert + transpose (+pad, +scale, +row-remap) ==============
// rowOff16 < 0: dst row = i.  rowOff16 >= 0: dst row = ((i>>4)<<5) + rowOff16 + (i&15)
// (interleaves two sources into 32-row groups: a rows at +0, g rows at +16).
__global__ void conv_tr(const float* __restrict__ src, size_t srcLayer, int srcStride,
                        int colOff, int R, int C,
                        bf16* __restrict__ dst, size_t dstLayer, int Tcols, float scale,
                        int rowOff16) {
  __shared__ float tile[32][33];
  const int i0 = blockIdx.x * 32, j0 = blockIdx.y * 32, z = blockIdx.z;
  const float* s = src + (size_t)z * srcLayer;
  bf16* d = dst + (size_t)z * dstLayer;
  const int tx = threadIdx.x, ty = threadIdx.y;
#pragma unroll
  for (int k = 0; k < 4; ++k) {
    int j = j0 + ty + k * 8;
    int i = i0 + tx;
    float v = 0.0f;
    if (j < R && i < C) v = s[(size_t)j * srcStride + colOff + i] * scale;
    tile[ty + k * 8][tx] = v;
  }
  __syncthreads();
#pragma unroll
  for (int k = 0; k < 4; ++k) {
    int i = i0 + ty + k * 8;   // logical dst row
    int j = j0 + tx;           // dst col
    int dr = (rowOff16 >= 0) ? (((i >> 4) << 5) + rowOff16 + (i & 15)) : i;
    d[(size_t)dr * Tcols + j] = (bf16)tile[tx][ty + k * 8];
  }
}

// ======================= LayerNorm ==========================
template <typename OUT>
__global__ void ln_kernel(const float* __restrict__ X, const float* __restrict__ G,
                          const float* __restrict__ Bt, OUT* __restrict__ out) {
  __shared__ float red[8];
  const int row = blockIdx.x, t = threadIdx.x;
  const float* xr = X + (size_t)row * DIM;
  float4 v = *(const float4*)(xr + t * 4);
  float s  = v.x + v.y + v.z + v.w;
  float s2 = v.x * v.x + v.y * v.y + v.z * v.z + v.w * v.w;
#pragma unroll
  for (int o = 1; o < 64; o <<= 1) { s += __shfl_xor(s, o); s2 += __shfl_xor(s2, o); }
  if ((t & 63) == 0) { red[t >> 6] = s; red[4 + (t >> 6)] = s2; }
  __syncthreads();
  float S  = red[0] + red[1] + red[2] + red[3];
  float S2 = red[4] + red[5] + red[6] + red[7];
  const float inv = 1.0f / (float)DIM;
  float mu = S * inv;
  float var = S2 * inv - mu * mu;
  float rstd = rsqrtf(var + 1e-5f);
  float4 g  = *(const float4*)(G + t * 4);
  float4 bb = *(const float4*)(Bt + t * 4);
  OUT* orow = out + (size_t)row * DIM + t * 4;
  orow[0] = (OUT)((v.x - mu) * rstd * g.x + bb.x);
  orow[1] = (OUT)((v.y - mu) * rstd * g.y + bb.y);
  orow[2] = (OUT)((v.z - mu) * rstd * g.z + bb.z);
  orow[3] = (OUT)((v.w - mu) * rstd * g.w + bb.w);
}

// ======================= GEMM 64x128 (2 blocks/CU; QKV/WO/FF2) =====================
// 64x128 tile, BK=64, 8 waves (2Mx4N, 32x32 each), double-buffered LDS (48KB),
// prefetch distance 1, 2 barriers/K-step. Doubled grids vs 128^2 -> 2 blocks/CU.
// Source-side swizzle + XCD block swizzle (nwg%8==0).
// MODE 0: store bf16 C. MODE 1: Xr += acc (fp32 residual).
// MODE 4: store bf16 C AND for cols>=576 also write V^T (VT=(bf16*)Xr):
//         VT[(b*64 + col-576)*NN + row], rows r=0..3 contiguous -> one bf16x4 store.
template <int MODE>
__launch_bounds__(512)
__global__ void gemm_bt64(const bf16* __restrict__ A, const bf16* __restrict__ B,
                          int K, int lda, int N, bf16* __restrict__ Cb, float* __restrict__ Xr) {
  __shared__ __align__(16) bf16 As[2][64 * 64];
  __shared__ __align__(16) bf16 Bs[2][128 * 64];
  const int tid = threadIdx.x;
  const int lane = tid & 63, wave = tid >> 6;
  const int gx = gridDim.x, gy = gridDim.y;
  const int nwg = gx * gy;
  const int orig = blockIdx.y * gx + blockIdx.x;
  const int wgid = (orig & 7) * (nwg >> 3) + (orig >> 3);  // XCD swizzle (nwg%8==0)
  const int m0 = (wgid % gy) * 64;    // M fastest within XCD chunk -> B-panel L2 reuse
  const int n0 = (wgid / gy) * 128;
  const int wm = (wave >> 2) * 32, wn = (wave & 3) * 32;
  const int fr = lane & 15, fg8 = (lane >> 4) * 8;
  const int frl8 = (fr & 7) * 8;           // read-side swizzle XOR
  const int rL = lane >> 3;                // staging row within 8-row group
  const int cS = ((lane & 7) ^ rL) * 8;    // pre-swizzled global source col
  const bf16* aB = A + (size_t)(m0 + wave * 8 + rL) * lda + cS;
  const bf16* bB = B + (size_t)(n0 + wave * 8 + rL) * K + cS;
  f32x4 acc[2][2] = {};

  auto STAGE = [&](int buf, int kt) {
    gload_lds16(aB + kt, &As[buf][wave * 512]);               // A: 64 rows, 1 chunk
#pragma unroll
    for (int r = 0; r < 2; ++r)                                // B: 128 rows, 2 chunks
      gload_lds16(bB + (size_t)(r * 64) * K + kt, &Bs[buf][(r * 8 + wave) * 512]);
  };

  STAGE(0, 0);
  const int nt = K >> 6;
  int cur = 0;
  for (int t = 0; t < nt; ++t) {
    asm volatile("s_waitcnt vmcnt(0)" ::: "memory");
    __builtin_amdgcn_s_barrier();
    __builtin_amdgcn_sched_barrier(0);
    if (t + 1 < nt) STAGE(cur ^ 1, (t + 1) * 64);
#pragma unroll
    for (int kk = 0; kk < 64; kk += 32) {
      bf16x8 af[2], bfr[2];
#pragma unroll
      for (int m = 0; m < 2; ++m)
        af[m] = *(const bf16x8*)&As[cur][(wm + m * 16 + fr) * 64 + ((kk + fg8) ^ frl8)];
#pragma unroll
      for (int n = 0; n < 2; ++n)
        bfr[n] = *(const bf16x8*)&Bs[cur][(wn + n * 16 + fr) * 64 + ((kk + fg8) ^ frl8)];
#pragma unroll
      for (int m = 0; m < 2; ++m)
#pragma unroll
        for (int n = 0; n < 2; ++n)
          acc[m][n] = __builtin_amdgcn_mfma_f32_16x16x32_bf16(af[m], bfr[n], acc[m][n], 0, 0, 0);
    }
    __builtin_amdgcn_sched_barrier(0);
    __builtin_amdgcn_s_barrier();
    cur ^= 1;
  }
  const int cc = lane & 15, cg = (lane >> 4) * 4;
#pragma unroll
  for (int m = 0; m < 2; ++m) {
#pragma unroll
    for (int n = 0; n < 2; ++n) {
      const int col = n0 + wn + n * 16 + cc;
      const int row0 = m0 + wm + m * 16 + cg;
#pragma unroll
      for (int r = 0; r < 4; ++r) {
        const size_t idx = (size_t)(row0 + r) * N + col;
        if (MODE == 0 || MODE == 4) Cb[idx] = (bf16)acc[m][n][r];
        else                        Xr[idx] += acc[m][n][r];
      }
      if (MODE == 4 && col >= 576) {   // V^T side-write (rows contiguous in VT)
        bf16* VT = (bf16*)Xr;
        const int bb2 = row0 >> 11;           // batch (NN=2048)
        const int nn2 = row0 & (NN - 1);
        bf16x4 v4;
#pragma unroll
        for (int r = 0; r < 4; ++r) v4[r] = (bf16)acc[m][n][r];
        *(bf16x4*)&VT[((size_t)(bb2 * 64 + (col - 576))) * NN + nn2] = v4;
      }
    }
  }
}

// ======================= GEMM m97-structure (for FF1: large grid) ==================
// 128x128 tile, BK=64, 4 waves (2x2, 64x64 each, 4x4 acc), SINGLE 32KB LDS buffer,
// sync/stage/sync/compute. 3-4 co-resident blocks/CU hide the stage drain.
// MODE 2: GEGLU epilogue (B rows interleaved 32-groups: a@+0..15, g@+16..31);
// writes gelu(g)*a compact with row stride N (pass N=FFP).
template <int MODE>
__launch_bounds__(256)
__global__ void gemm97(const bf16* __restrict__ A, const bf16* __restrict__ B,
                       int K, int lda, int N, bf16* __restrict__ Cb, float* __restrict__ Xr) {
  __shared__ __align__(16) bf16 As[128 * 64];
  __shared__ __align__(16) bf16 Bs[128 * 64];
  const int tid = threadIdx.x;
  const int lane = tid & 63, wave = tid >> 6;
  const int gx = gridDim.x, gy = gridDim.y;
  const int nwg = gx * gy;
  const int orig = blockIdx.y * gx + blockIdx.x;
  const int wgid = (orig & 7) * (nwg >> 3) + (orig >> 3);  // XCD swizzle (nwg%8==0)
  const int m0 = (wgid % gy) * 128;
  const int n0 = (wgid / gy) * 128;
  const int wm = (wave >> 1) * 64, wn = (wave & 1) * 64;
  const int fr = lane & 15, fg8 = (lane >> 4) * 8;
  const int frl8 = (fr & 7) * 8;
  const int rL = lane >> 3;
  const int cS = ((lane & 7) ^ rL) * 8;
  const bf16* aB = A + (size_t)(m0 + wave * 8 + rL) * lda + cS;
  const bf16* bB = B + (size_t)(n0 + wave * 8 + rL) * K + cS;
  f32x4 acc[4][4] = {};

  for (int kt = 0; kt < K; kt += 64) {
    __syncthreads();   // previous compute done reading LDS
#pragma unroll
    for (int r = 0; r < 4; ++r) {
      gload_lds16(aB + (size_t)(r * 32) * lda + kt, &As[(r * 4 + wave) * 512]);
      gload_lds16(bB + (size_t)(r * 32) * K + kt, &Bs[(r * 4 + wave) * 512]);
    }
    __syncthreads();   // drains vmcnt(0): DMA complete (compiler-inserted)
#pragma unroll
    for (int kk = 0; kk < 64; kk += 32) {
      bf16x8 af[4], bfr[4];
#pragma unroll
      for (int m = 0; m < 4; ++m)
        af[m] = *(const bf16x8*)&As[(wm + m * 16 + fr) * 64 + ((kk + fg8) ^ frl8)];
#pragma unroll
      for (int n = 0; n < 4; ++n)
        bfr[n] = *(const bf16x8*)&Bs[(wn + n * 16 + fr) * 64 + ((kk + fg8) ^ frl8)];
#pragma unroll
      for (int m = 0; m < 4; ++m)
#pragma unroll
        for (int n = 0; n < 4; ++n)
          acc[m][n] = __builtin_amdgcn_mfma_f32_16x16x32_bf16(af[m], bfr[n], acc[m][n], 0, 0, 0);
    }
  }
  const int cc = lane & 15, cg = (lane >> 4) * 4;
  if (MODE == 2) {
    const int jbase = (n0 + wn) / 2 + cc;
#pragma unroll
    for (int m = 0; m < 4; ++m) {
#pragma unroll
      for (int p = 0; p < 2; ++p) {
#pragma unroll
        for (int r = 0; r < 4; ++r) {
          const int row = m0 + wm + m * 16 + cg + r;
          const float av = acc[m][2 * p][r], gv = acc[m][2 * p + 1][r];
          const float ge = 0.5f * gv * (1.0f + erff(gv * 0.70710678118654752f)) * av;
          Cb[(size_t)row * N + jbase + p * 16] = (bf16)ge;
        }
      }
    }
  } else {
#pragma unroll
    for (int m = 0; m < 4; ++m) {
#pragma unroll
      for (int n = 0; n < 4; ++n) {
        const int col = n0 + wn + n * 16 + cc;
#pragma unroll
        for (int r = 0; r < 4; ++r) {
          const int row = m0 + wm + m * 16 + cg + r;
          const size_t idx = (size_t)row * N + col;
          if (MODE == 0) Cb[idx] = (bf16)acc[m][n][r];
          else           Xr[idx] += acc[m][n][r];
        }
      }
    }
  }
}

// ======================= attention: 32x32 MFMA, in-register softmax ==============
// 4 waves/block = 4 heads (MQA: K/V shared -> L1 reuse), no barriers, no LDS.
// NSPLIT=4 KV splits -> 1024 blocks. Partials q-major Opart[split][bh][q][64] in
// BF16 (unnormalized sums; ~0.4% rel error << threshold) -> halves partial traffic.
__launch_bounds__(256)
__global__ void attn_kernel(const bf16* __restrict__ QKV, const bf16* __restrict__ VT,
                            const float* __restrict__ btab,
                            bf16* __restrict__ Opart, float* __restrict__ mlbuf) {
  const int tid = threadIdx.x;
  const int lane = tid & 63, wv = tid >> 6;
  const int split = blockIdx.x & (NSPLIT - 1);
  const int qt = (NN / 32 - 1) - (blockIdx.x / NSPLIT);   // longest-first
  const int h = blockIdx.y * 4 + wv, b = blockIdx.z;
  const int q0 = qt * 32;
  const int qc = lane & 31;        // q col (also A-operand row index, also V^T d row)
  const int hid = lane >> 5;
  const int h8 = hid * 8;
  const int kv_full = q0 + 32;
  // distribute 32-row tiles among NSPLIT splits
  const int nt32 = kv_full >> 5;
  const int base = nt32 >> 2, rem = nt32 & 3;
  const int cnt = base + (split < rem ? 1 : 0);
  const int startT = split * base + (split < rem ? split : rem);
  const int lo = startT * 32;
  const int kend = lo + cnt * 32;
  const size_t obase = ((size_t)(split * NB * NH) + b * NH + h) * NN;  // q-row base
  const int Rbase = (b * NH + h) * NN + q0;
  bf16* prow = Opart + (obase + q0 + qc) * 64;
  if (cnt == 0) {   // empty split: zero partial block, weight 0 in combine
    const bf16x4 z4 = {(bf16)0.f, (bf16)0.f, (bf16)0.f, (bf16)0.f};
#pragma unroll
    for (int g = 0; g < 8; ++g) *(bf16x4*)&prow[g * 8 + 4 * hid] = z4;
    if (hid == 0)
      ((float2*)mlbuf)[(size_t)split * AROWS + Rbase + qc] = make_float2(-1e30f, 0.0f);
    return;
  }
  const float* bt = btab + h * NN;
  bf16x8 qf[4];
#pragma unroll
  for (int ks = 0; ks < 4; ++ks)
    qf[ks] = *(const bf16x8*)&QKV[(size_t)(b * NN + q0 + qc) * QKVN + h * DH + ks * 16 + h8];

  f32x16 Oacc0 = {}, Oacc1 = {};
  float m_run = -1e30f, l_run = 0.0f;
  int kv0 = lo;

  while (kv0 < kend) {
    const bool interior = (kv0 + 32 <= q0);
    bf16x8 kf[4];
#pragma unroll
    for (int ks = 0; ks < 4; ++ks)
      kf[ks] = *(const bf16x8*)&QKV[(size_t)(b * NN + kv0 + qc) * QKVN + 512 + ks * 16 + h8];
    bf16x8 vf[2][2];
#pragma unroll
    for (int dblk = 0; dblk < 2; ++dblk)
#pragma unroll
      for (int ks2 = 0; ks2 < 2; ++ks2)
        vf[dblk][ks2] = *(const bf16x8*)&VT[(size_t)(b * 64 + dblk * 32 + qc) * NN + kv0 + ks2 * 16 + h8];
    __builtin_amdgcn_s_setprio(1);
    f32x16 S = {};
#pragma unroll
    for (int ks = 0; ks < 4; ++ks)
      S = __builtin_amdgcn_mfma_f32_32x32x16_bf16(kf[ks], qf[ks], S, 0, 0, 0);
    __builtin_amdgcn_s_setprio(0);
    float sv[16];
    float mx = -1e30f;
    if (interior) {
      f32x4 bv[4];
#pragma unroll
      for (int g = 0; g < 4; ++g)
        bv[g] = *(const f32x4u*)(bt + (q0 + qc - kv0 - 8 * g - 4 * hid - 3));
#pragma unroll
      for (int g = 0; g < 4; ++g)
#pragma unroll
        for (int e = 0; e < 4; ++e) {
          const float val = S[g * 4 + e] + bv[g][3 - e];
          sv[g * 4 + e] = val;
          mx = fmaxf(mx, val);
        }
    } else {
#pragma unroll
      for (int r = 0; r < 16; ++r) {
        const int kvr = (r & 3) + 8 * (r >> 2) + 4 * hid;
        const int d = (q0 + qc) - (kv0 + kvr);
        const int dc = d > 0 ? d : 0;
        float val = S[r] + bt[dc];
        if (d < 0) val = -1e30f;
        sv[r] = val;
        mx = fmaxf(mx, val);
      }
    }
    if (!__all(mx <= m_run + 8.0f)) {
      mx = fmaxf(mx, __shfl_xor(mx, 32));
      const float m_new = fmaxf(m_run, mx);
      const float sc = __expf(m_run - m_new);
      l_run *= sc;
#pragma unroll
      for (int r = 0; r < 16; ++r) { Oacc0[r] *= sc; Oacc1[r] *= sc; }
      m_run = m_new;
    }
    float csum = 0.0f;
#pragma unroll
    for (int r = 0; r < 16; ++r) { sv[r] = __expf(sv[r] - m_run); csum += sv[r]; }
    csum += __shfl_xor(csum, 32);
    l_run += csum;
    int w[8];
#pragma unroll
    for (int g = 0; g < 4; ++g) {
      w[2 * g]     = pack_bf16(sv[4 * g],     sv[4 * g + 1]);
      w[2 * g + 1] = pack_bf16(sv[4 * g + 2], sv[4 * g + 3]);
    }
    bf16x8 pfrag[2];
#pragma unroll
    for (int ks2 = 0; ks2 < 2; ++ks2) {
      const int a  = w[4 * ks2],     bb = w[4 * ks2 + 1];
      const int c  = w[4 * ks2 + 2], dd = w[4 * ks2 + 3];
      const int s0 = hid ? a : c,    s1 = hid ? bb : dd;
      const int r0 = __shfl_xor(s0, 32);
      const int r1 = __shfl_xor(s1, 32);
      i32x4 fw;
      fw[0] = hid ? r0 : a;
      fw[1] = hid ? r1 : bb;
      fw[2] = hid ? c  : r0;
      fw[3] = hid ? dd : r1;
      pfrag[ks2] = __builtin_bit_cast(bf16x8, fw);
    }
    __builtin_amdgcn_s_setprio(1);
#pragma unroll
    for (int ks2 = 0; ks2 < 2; ++ks2) {
      Oacc0 = __builtin_amdgcn_mfma_f32_32x32x16_bf16(vf[0][ks2], pfrag[ks2], Oacc0, 0, 0, 0);
      Oacc1 = __builtin_amdgcn_mfma_f32_32x32x16_bf16(vf[1][ks2], pfrag[ks2], Oacc1, 0, 0, 0);
    }
    __builtin_amdgcn_s_setprio(0);
    kv0 += 32;
  }
  // dl = (r&3) + 8*(r>>2) + 4*hid: groups of 4 consecutive -> bf16x4 stores
#pragma unroll
  for (int g = 0; g < 4; ++g) {
    bf16x4 v0, v1;
#pragma unroll
    for (int j = 0; j < 4; ++j) { v0[j] = (bf16)Oacc0[g * 4 + j]; v1[j] = (bf16)Oacc1[g * 4 + j]; }
    *(bf16x4*)&prow[g * 8 + 4 * hid]      = v0;
    *(bf16x4*)&prow[32 + g * 8 + 4 * hid] = v1;
  }
  if (hid == 0)
    ((float2*)mlbuf)[(size_t)split * AROWS + Rbase + qc] = make_float2(m_run, l_run);
}

// ======================= combine split-KV partials -> O (bf16) =================
// Opart layout: [split][bh][NN q][64 d] bf16 (q-major), dq-fastest thread mapping.
__global__ void attn_combine(const bf16* __restrict__ Opart, const float* __restrict__ mlbuf,
                             bf16* __restrict__ O) {
  const int gtid = blockIdx.x * 256 + threadIdx.x;   // NB*NH*NN*16 threads
  const int dq = gtid & 15;
  const int q  = (gtid >> 4) & (NN - 1);
  const int bh = gtid >> 15;                          // b*NH + h
  const int R = bh * NN + q;
  float2 ml[NSPLIT];
  float m = -1e30f;
#pragma unroll
  for (int s = 0; s < NSPLIT; ++s) {
    ml[s] = ((const float2*)mlbuf)[(size_t)s * AROWS + R];
    m = fmaxf(m, ml[s].x);
  }
  float w[NSPLIT];
  float denom = 0.0f;
#pragma unroll
  for (int s = 0; s < NSPLIT; ++s) {
    w[s] = __expf(ml[s].x - m);
    denom += ml[s].y * w[s];
  }
  const float inv = 1.0f / denom;
  float o[4] = {};
#pragma unroll
  for (int s = 0; s < NSPLIT; ++s) {
    const bf16x4 v = *(const bf16x4*)(Opart + ((size_t)(s * NB * NH + bh) * NN + q) * 64 + dq * 4);
#pragma unroll
    for (int j = 0; j < 4; ++j) o[j] += (float)v[j] * w[s];
  }
  bf16x4 res;
#pragma unroll
  for (int j = 0; j < 4; ++j) res[j] = (bf16)(o[j] * inv);
  const int h = bh & (NH - 1), b = bh >> 3;
  *(bf16x4*)&O[(size_t)(b * NN + q) * INNER + h * DH + dq * 4] = res;
}

// ======================= launch ==========================
extern "C" void kernel_launch(void* const* d_in, const int* in_sizes, int n_in,
                              void* d_out, int out_size, void* d_ws, size_t ws_size,
                              hipStream_t stream) {
  (void)in_sizes; (void)n_in; (void)out_size;
  const float* in_x  = (const float*)d_in[0];
  const float* rel   = (const float*)d_in[1];
  const float* ln1g  = (const float*)d_in[2];
  const float* ln1b  = (const float*)d_in[3];
  const float* wq    = (const float*)d_in[4];
  const float* wkv   = (const float*)d_in[5];
  const float* wo    = (const float*)d_in[6];
  const float* ln2g  = (const float*)d_in[7];
  const float* ln2b  = (const float*)d_in[8];
  const float* w1    = (const float*)d_in[9];
  const float* w2    = (const float*)d_in[10];
  const float* lnfg  = (const float*)d_in[11];
  const float* lnfb  = (const float*)d_in[12];
  float* out = (float*)d_out;

  constexpr size_t E_QKV = (size_t)QKVN * DIM;   // fused wq|wkv, [640][1024]
  constexpr size_t E_WO  = (size_t)DIM * INNER;
  constexpr size_t E_W1F = (size_t)FF2N * DIM;   // interleaved a/g [5632][1024]
  constexpr size_t E_W2  = (size_t)DIM * FFP;
  bf16* wqkvT = (bf16*)d_ws;
  bf16* woT  = wqkvT + NLAY * E_QKV;
  bf16* w1fT = woT  + NLAY * E_WO;
  bf16* w2T  = w1fT + NLAY * E_W1F;
  bf16* xnb  = w2T  + NLAY * E_W2;
  bf16* qkvb = xnb  + (size_t)MROW * DIM;
  bf16* vTb  = qkvb + (size_t)MROW * QKVN;
  bf16* ob   = vTb  + (size_t)NB * 64 * NN;
  bf16* hb   = ob   + (size_t)MROW * INNER;      // FF phase: compact [4096][FFP]
  float* xbuf = (float*)(hb + (size_t)MROW * FF2N);
  float* btab = xbuf + (size_t)MROW * DIM;
  const size_t needed = (size_t)((char*)(btab + NH * NN) - (char*)d_ws);
  if (ws_size < needed) return;  // visible clean failure instead of corruption
  // attn partials overlaid on hb (FF phase and attn phase are disjoint in time):
  // Opart bf16: 4 splits*16 bh*2048 q*64 d*2B = 16.8MB; mlbuf at +18MB (hb is 46MB)
  bf16* Opart = hb;
  float* mlbuf = (float*)(hb + (size_t)9 * 1024 * 1024);
  hipMemcpyAsync(xbuf, in_x, (size_t)MROW * DIM * sizeof(float),
                 hipMemcpyDeviceToDevice, stream);
  btab_kernel<<<8, 256, 0, stream>>>(rel, btab);

  const dim3 tb(32, 8);
  conv_tr<<<dim3(16, 32, 6), tb, 0, stream>>>(wq,  (size_t)DIM*INNER, INNER, 0, DIM, INNER,
                                              wqkvT, E_QKV, DIM, 0.125f, -1);  // fold DH^-0.5
  conv_tr<<<dim3(4, 32, 6),  tb, 0, stream>>>(wkv, (size_t)DIM*128, 128, 0, DIM, 128,
                                              wqkvT + (size_t)INNER*DIM, E_QKV, DIM, 1.0f, -1);
  conv_tr<<<dim3(32, 16, 6), tb, 0, stream>>>(wo,  (size_t)INNER*DIM, DIM, 0, INNER, DIM,
                                              woT,  E_WO, INNER, 1.0f, -1);
  conv_tr<<<dim3(88, 32, 6), tb, 0, stream>>>(w1,  (size_t)DIM*2*FF, 2*FF, 0, DIM, FF,
                                              w1fT, E_W1F, DIM, 1.0f, 0);    // a rows -> +0
  conv_tr<<<dim3(88, 32, 6), tb, 0, stream>>>(w1,  (size_t)DIM*2*FF, 2*FF, FF, DIM, FF,
                                              w1fT, E_W1F, DIM, 1.0f, 16);   // g rows -> +16
  conv_tr<<<dim3(32, 88, 6), tb, 0, stream>>>(w2,  (size_t)FF*DIM, DIM, 0, FF, DIM,
                                              w2T,  E_W2, FFP, 1.0f, -1);

  for (int l = 0; l < NLAY; ++l) {
    ln_kernel<bf16><<<MROW, 256, 0, stream>>>(xbuf, ln1g + l*DIM, ln1b + l*DIM, xnb);
    gemm_bt64<4><<<dim3(QKVN/128, MROW/64), 512, 0, stream>>>(xnb, wqkvT + l*E_QKV, DIM, DIM, QKVN, qkvb, (float*)vTb);
    attn_kernel<<<dim3((NN/32)*NSPLIT, NH/4, NB), 256, 0, stream>>>(qkvb, vTb, btab, Opart, mlbuf);
    attn_combine<<<AROWS*16/256, 256, 0, stream>>>(Opart, mlbuf, ob);
    gemm_bt64<1><<<dim3(DIM/128, MROW/64), 512, 0, stream>>>(ob, woT + l*E_WO, INNER, INNER, DIM, nullptr, xbuf);
    ln_kernel<bf16><<<MROW, 256, 0, stream>>>(xbuf, ln2g + l*DIM, ln2b + l*DIM, xnb);
    gemm97<2><<<dim3(FF2N/128, MROW/128), 256, 0, stream>>>(xnb, w1fT + l*E_W1F, DIM, DIM, FFP, hb, nullptr);
    gemm_bt64<1><<<dim3(DIM/128, MROW/64), 512, 0, stream>>>(hb, w2T + l*E_W2, FFP, FFP, DIM, nullptr, xbuf);
  }
  ln_kernel<float><<<MROW, 256, 0, stream>>>(xbuf, lnfg, lnfb, out);
}

// Round 17
// 1449.961 us; speedup vs baseline: 1.1438x; 1.0080x over previous
//
#include <hip/hip_runtime.h>
#include <cstdint>
#include <cstddef>

using bf16 = __bf16;
typedef __bf16 bf16x8 __attribute__((ext_vector_type(8)));
typedef __bf16 bf16x4 __attribute__((ext_vector_type(4)));
typedef __bf16 bf16x2 __attribute__((ext_vector_type(2)));
typedef float  f32x4  __attribute__((ext_vector_type(4)));
typedef float  f32x16 __attribute__((ext_vector_type(16)));
typedef int    i32x4  __attribute__((ext_vector_type(4)));
typedef float  f32x4u __attribute__((ext_vector_type(4), aligned(4)));  // 4B-aligned vec load

// ---- problem constants ----
constexpr int NB   = 2;      // batch
constexpr int NN   = 2048;   // seq
constexpr int DIM  = 1024;
constexpr int NH   = 8;
constexpr int DH   = 64;
constexpr int INNER= 512;
constexpr int QKVN = 640;    // fused Q(512) + K(64) + V(64) projection width
constexpr int FF   = 2730;
constexpr int FFP  = 2816;   // padded FF (22*128)
constexpr int FF2N = 5632;   // fused a|g FF1 output width (interleaved 32-groups)
constexpr int MROW = NB * NN;   // 4096
constexpr int NLAY = 6;
constexpr int AROWS = NB * NH * NN;  // 32768 attention (b,h,q) rows
constexpr int NSPLIT = 8;            // KV splits (2048 blocks -> 6 waves/SIMD, VGPR-capped)

// async global->LDS, 16B per lane; LDS dest is wave-uniform base (+lane*16 by HW)
__device__ __forceinline__ void gload_lds16(const bf16* g, bf16* l) {
  __builtin_amdgcn_global_load_lds((const __attribute__((address_space(1))) void*)g,
                                   (__attribute__((address_space(3))) void*)l,
                                   16, 0, 0);
}

__device__ __forceinline__ int pack_bf16(float lo, float hi_) {
  bf16x2 t; t[0] = (bf16)lo; t[1] = (bf16)hi_;
  return __builtin_bit_cast(int, t);
}

// ======================= bias table ==========================
__global__ void btab_kernel(const float* __restrict__ rel, float* __restrict__ btab) {
  int d = blockIdx.x * 256 + threadIdx.x;
  if (d >= NN) return;
  int bucket;
  if (d < 16) bucket = d;
  else {
    int vl = 16 + (int)(logf((float)d / 16.0f) / logf(8.0f) * 16.0f);
    bucket = vl < 31 ? vl : 31;
  }
  for (int h = 0; h < NH; ++h) btab[h * NN + d] = rel[bucket * NH + h];
}

// ============== weight convert + transpose (+pad, +scale, +row-remap) ==============
// rowOff16 < 0: dst row = i.  rowOff16 >= 0: dst row = ((i>>4)<<5) + rowOff16 + (i&15)
// (interleaves two sources into 32-row groups: a rows at +0, g rows at +16).
__global__ void conv_tr(const float* __restrict__ src, size_t srcLayer, int srcStride,
                        int colOff, int R, int C,
                        bf16* __restrict__ dst, size_t dstLayer, int Tcols, float scale,
                        int rowOff16) {
  __shared__ float tile[32][33];
  const int i0 = blockIdx.x * 32, j0 = blockIdx.y * 32, z = blockIdx.z;
  const float* s = src + (size_t)z * srcLayer;
  bf16* d = dst + (size_t)z * dstLayer;
  const int tx = threadIdx.x, ty = threadIdx.y;
#pragma unroll
  for (int k = 0; k < 4; ++k) {
    int j = j0 + ty + k * 8;
    int i = i0 + tx;
    float v = 0.0f;
    if (j < R && i < C) v = s[(size_t)j * srcStride + colOff + i] * scale;
    tile[ty + k * 8][tx] = v;
  }
  __syncthreads();
#pragma unroll
  for (int k = 0; k < 4; ++k) {
    int i = i0 + ty + k * 8;   // logical dst row
    int j = j0 + tx;           // dst col
    int dr = (rowOff16 >= 0) ? (((i >> 4) << 5) + rowOff16 + (i & 15)) : i;
    d[(size_t)dr * Tcols + j] = (bf16)tile[tx][ty + k * 8];
  }
}

// ======================= LayerNorm ==========================
template <typename OUT>
__global__ void ln_kernel(const float* __restrict__ X, const float* __restrict__ G,
                          const float* __restrict__ Bt, OUT* __restrict__ out) {
  __shared__ float red[8];
  const int row = blockIdx.x, t = threadIdx.x;
  const float* xr = X + (size_t)row * DIM;
  float4 v = *(const float4*)(xr + t * 4);
  float s  = v.x + v.y + v.z + v.w;
  float s2 = v.x * v.x + v.y * v.y + v.z * v.z + v.w * v.w;
#pragma unroll
  for (int o = 1; o < 64; o <<= 1) { s += __shfl_xor(s, o); s2 += __shfl_xor(s2, o); }
  if ((t & 63) == 0) { red[t >> 6] = s; red[4 + (t >> 6)] = s2; }
  __syncthreads();
  float S  = red[0] + red[1] + red[2] + red[3];
  float S2 = red[4] + red[5] + red[6] + red[7];
  const float inv = 1.0f / (float)DIM;
  float mu = S * inv;
  float var = S2 * inv - mu * mu;
  float rstd = rsqrtf(var + 1e-5f);
  float4 g  = *(const float4*)(G + t * 4);
  float4 bb = *(const float4*)(Bt + t * 4);
  OUT* orow = out + (size_t)row * DIM + t * 4;
  orow[0] = (OUT)((v.x - mu) * rstd * g.x + bb.x);
  orow[1] = (OUT)((v.y - mu) * rstd * g.y + bb.y);
  orow[2] = (OUT)((v.z - mu) * rstd * g.z + bb.z);
  orow[3] = (OUT)((v.w - mu) * rstd * g.w + bb.w);
}

// ======================= GEMM 64x128 (2 blocks/CU; QKV/WO/FF2) =====================
// 64x128 tile, BK=64, 8 waves (2Mx4N, 32x32 each), double-buffered LDS (48KB),
// prefetch distance 1, 2 barriers/K-step. Doubled grids vs 128^2 -> 2 blocks/CU.
// Source-side swizzle + XCD block swizzle (nwg%8==0).
// MODE 0: store bf16 C. MODE 1: Xr += acc (fp32 residual).
// MODE 4: store bf16 C AND for cols>=576 also write V^T (VT=(bf16*)Xr):
//         VT[(b*64 + col-576)*NN + row], rows r=0..3 contiguous -> one bf16x4 store.
template <int MODE>
__launch_bounds__(512)
__global__ void gemm_bt64(const bf16* __restrict__ A, const bf16* __restrict__ B,
                          int K, int lda, int N, bf16* __restrict__ Cb, float* __restrict__ Xr) {
  __shared__ __align__(16) bf16 As[2][64 * 64];
  __shared__ __align__(16) bf16 Bs[2][128 * 64];
  const int tid = threadIdx.x;
  const int lane = tid & 63, wave = tid >> 6;
  const int gx = gridDim.x, gy = gridDim.y;
  const int nwg = gx * gy;
  const int orig = blockIdx.y * gx + blockIdx.x;
  const int wgid = (orig & 7) * (nwg >> 3) + (orig >> 3);  // XCD swizzle (nwg%8==0)
  const int m0 = (wgid % gy) * 64;    // M fastest within XCD chunk -> B-panel L2 reuse
  const int n0 = (wgid / gy) * 128;
  const int wm = (wave >> 2) * 32, wn = (wave & 3) * 32;
  const int fr = lane & 15, fg8 = (lane >> 4) * 8;
  const int frl8 = (fr & 7) * 8;           // read-side swizzle XOR
  const int rL = lane >> 3;                // staging row within 8-row group
  const int cS = ((lane & 7) ^ rL) * 8;    // pre-swizzled global source col
  const bf16* aB = A + (size_t)(m0 + wave * 8 + rL) * lda + cS;
  const bf16* bB = B + (size_t)(n0 + wave * 8 + rL) * K + cS;
  f32x4 acc[2][2] = {};

  auto STAGE = [&](int buf, int kt) {
    gload_lds16(aB + kt, &As[buf][wave * 512]);               // A: 64 rows, 1 chunk
#pragma unroll
    for (int r = 0; r < 2; ++r)                                // B: 128 rows, 2 chunks
      gload_lds16(bB + (size_t)(r * 64) * K + kt, &Bs[buf][(r * 8 + wave) * 512]);
  };

  STAGE(0, 0);
  const int nt = K >> 6;
  int cur = 0;
  for (int t = 0; t < nt; ++t) {
    asm volatile("s_waitcnt vmcnt(0)" ::: "memory");
    __builtin_amdgcn_s_barrier();
    __builtin_amdgcn_sched_barrier(0);
    if (t + 1 < nt) STAGE(cur ^ 1, (t + 1) * 64);
#pragma unroll
    for (int kk = 0; kk < 64; kk += 32) {
      bf16x8 af[2], bfr[2];
#pragma unroll
      for (int m = 0; m < 2; ++m)
        af[m] = *(const bf16x8*)&As[cur][(wm + m * 16 + fr) * 64 + ((kk + fg8) ^ frl8)];
#pragma unroll
      for (int n = 0; n < 2; ++n)
        bfr[n] = *(const bf16x8*)&Bs[cur][(wn + n * 16 + fr) * 64 + ((kk + fg8) ^ frl8)];
#pragma unroll
      for (int m = 0; m < 2; ++m)
#pragma unroll
        for (int n = 0; n < 2; ++n)
          acc[m][n] = __builtin_amdgcn_mfma_f32_16x16x32_bf16(af[m], bfr[n], acc[m][n], 0, 0, 0);
    }
    __builtin_amdgcn_sched_barrier(0);
    __builtin_amdgcn_s_barrier();
    cur ^= 1;
  }
  const int cc = lane & 15, cg = (lane >> 4) * 4;
#pragma unroll
  for (int m = 0; m < 2; ++m) {
#pragma unroll
    for (int n = 0; n < 2; ++n) {
      const int col = n0 + wn + n * 16 + cc;
      const int row0 = m0 + wm + m * 16 + cg;
#pragma unroll
      for (int r = 0; r < 4; ++r) {
        const size_t idx = (size_t)(row0 + r) * N + col;
        if (MODE == 0 || MODE == 4) Cb[idx] = (bf16)acc[m][n][r];
        else                        Xr[idx] += acc[m][n][r];
      }
      if (MODE == 4 && col >= 576) {   // V^T side-write (rows contiguous in VT)
        bf16* VT = (bf16*)Xr;
        const int bb2 = row0 >> 11;           // batch (NN=2048)
        const int nn2 = row0 & (NN - 1);
        bf16x4 v4;
#pragma unroll
        for (int r = 0; r < 4; ++r) v4[r] = (bf16)acc[m][n][r];
        *(bf16x4*)&VT[((size_t)(bb2 * 64 + (col - 576))) * NN + nn2] = v4;
      }
    }
  }
}

// ======================= GEMM m97-structure (for FF1: large grid) ==================
// 128x128 tile, BK=64, 4 waves (2x2, 64x64 each, 4x4 acc), SINGLE 32KB LDS buffer,
// sync/stage/sync/compute. 3-4 co-resident blocks/CU hide the stage drain.
// MODE 2: GEGLU epilogue (B rows interleaved 32-groups: a@+0..15, g@+16..31);
// writes gelu(g)*a compact with row stride N (pass N=FFP).
template <int MODE>
__launch_bounds__(256)
__global__ void gemm97(const bf16* __restrict__ A, const bf16* __restrict__ B,
                       int K, int lda, int N, bf16* __restrict__ Cb, float* __restrict__ Xr) {
  __shared__ __align__(16) bf16 As[128 * 64];
  __shared__ __align__(16) bf16 Bs[128 * 64];
  const int tid = threadIdx.x;
  const int lane = tid & 63, wave = tid >> 6;
  const int gx = gridDim.x, gy = gridDim.y;
  const int nwg = gx * gy;
  const int orig = blockIdx.y * gx + blockIdx.x;
  const int wgid = (orig & 7) * (nwg >> 3) + (orig >> 3);  // XCD swizzle (nwg%8==0)
  const int m0 = (wgid % gy) * 128;
  const int n0 = (wgid / gy) * 128;
  const int wm = (wave >> 1) * 64, wn = (wave & 1) * 64;
  const int fr = lane & 15, fg8 = (lane >> 4) * 8;
  const int frl8 = (fr & 7) * 8;
  const int rL = lane >> 3;
  const int cS = ((lane & 7) ^ rL) * 8;
  const bf16* aB = A + (size_t)(m0 + wave * 8 + rL) * lda + cS;
  const bf16* bB = B + (size_t)(n0 + wave * 8 + rL) * K + cS;
  f32x4 acc[4][4] = {};

  for (int kt = 0; kt < K; kt += 64) {
    __syncthreads();   // previous compute done reading LDS
#pragma unroll
    for (int r = 0; r < 4; ++r) {
      gload_lds16(aB + (size_t)(r * 32) * lda + kt, &As[(r * 4 + wave) * 512]);
      gload_lds16(bB + (size_t)(r * 32) * K + kt, &Bs[(r * 4 + wave) * 512]);
    }
    __syncthreads();   // drains vmcnt(0): DMA complete (compiler-inserted)
#pragma unroll
    for (int kk = 0; kk < 64; kk += 32) {
      bf16x8 af[4], bfr[4];
#pragma unroll
      for (int m = 0; m < 4; ++m)
        af[m] = *(const bf16x8*)&As[(wm + m * 16 + fr) * 64 + ((kk + fg8) ^ frl8)];
#pragma unroll
      for (int n = 0; n < 4; ++n)
        bfr[n] = *(const bf16x8*)&Bs[(wn + n * 16 + fr) * 64 + ((kk + fg8) ^ frl8)];
#pragma unroll
      for (int m = 0; m < 4; ++m)
#pragma unroll
        for (int n = 0; n < 4; ++n)
          acc[m][n] = __builtin_amdgcn_mfma_f32_16x16x32_bf16(af[m], bfr[n], acc[m][n], 0, 0, 0);
    }
  }
  const int cc = lane & 15, cg = (lane >> 4) * 4;
  if (MODE == 2) {
    const int jbase = (n0 + wn) / 2 + cc;
#pragma unroll
    for (int m = 0; m < 4; ++m) {
#pragma unroll
      for (int p = 0; p < 2; ++p) {
#pragma unroll
        for (int r = 0; r < 4; ++r) {
          const int row = m0 + wm + m * 16 + cg + r;
          const float av = acc[m][2 * p][r], gv = acc[m][2 * p + 1][r];
          const float ge = 0.5f * gv * (1.0f + erff(gv * 0.70710678118654752f)) * av;
          Cb[(size_t)row * N + jbase + p * 16] = (bf16)ge;
        }
      }
    }
  } else {
#pragma unroll
    for (int m = 0; m < 4; ++m) {
#pragma unroll
      for (int n = 0; n < 4; ++n) {
        const int col = n0 + wn + n * 16 + cc;
#pragma unroll
        for (int r = 0; r < 4; ++r) {
          const int row = m0 + wm + m * 16 + cg + r;
          const size_t idx = (size_t)row * N + col;
          if (MODE == 0) Cb[idx] = (bf16)acc[m][n][r];
          else           Xr[idx] += acc[m][n][r];
        }
      }
    }
  }
}

// ======================= attention: 32x32 MFMA, in-register softmax ==============
// 4 waves/block = 4 heads (MQA: K/V shared -> L1 reuse), no barriers, no LDS.
// NSPLIT=8 KV splits -> 2048 blocks = 6 waves/SIMD (VGPR-capped). Partials q-major
// Opart[split][bh][q][64] in BF16 (~0.4% rel error << threshold).
__launch_bounds__(256)
__global__ void attn_kernel(const bf16* __restrict__ QKV, const bf16* __restrict__ VT,
                            const float* __restrict__ btab,
                            bf16* __restrict__ Opart, float* __restrict__ mlbuf) {
  const int tid = threadIdx.x;
  const int lane = tid & 63, wv = tid >> 6;
  const int split = blockIdx.x & (NSPLIT - 1);
  const int qt = (NN / 32 - 1) - (blockIdx.x / NSPLIT);   // longest-first
  const int h = blockIdx.y * 4 + wv, b = blockIdx.z;
  const int q0 = qt * 32;
  const int qc = lane & 31;        // q col (also A-operand row index, also V^T d row)
  const int hid = lane >> 5;
  const int h8 = hid * 8;
  const int kv_full = q0 + 32;
  // distribute 32-row tiles among NSPLIT splits
  const int nt32 = kv_full >> 5;
  const int base = nt32 / NSPLIT, rem = nt32 & (NSPLIT - 1);
  const int cnt = base + (split < rem ? 1 : 0);
  const int startT = split * base + (split < rem ? split : rem);
  const int lo = startT * 32;
  const int kend = lo + cnt * 32;
  const size_t obase = ((size_t)(split * NB * NH) + b * NH + h) * NN;  // q-row base
  const int Rbase = (b * NH + h) * NN + q0;
  bf16* prow = Opart + (obase + q0 + qc) * 64;
  if (cnt == 0) {   // empty split: zero partial block, weight 0 in combine
    const bf16x4 z4 = {(bf16)0.f, (bf16)0.f, (bf16)0.f, (bf16)0.f};
#pragma unroll
    for (int g = 0; g < 8; ++g) *(bf16x4*)&prow[g * 8 + 4 * hid] = z4;
    if (hid == 0)
      ((float2*)mlbuf)[(size_t)split * AROWS + Rbase + qc] = make_float2(-1e30f, 0.0f);
    return;
  }
  const float* bt = btab + h * NN;
  bf16x8 qf[4];
#pragma unroll
  for (int ks = 0; ks < 4; ++ks)
    qf[ks] = *(const bf16x8*)&QKV[(size_t)(b * NN + q0 + qc) * QKVN + h * DH + ks * 16 + h8];

  f32x16 Oacc0 = {}, Oacc1 = {};
  float m_run = -1e30f, l_run = 0.0f;
  int kv0 = lo;

  while (kv0 < kend) {
    const bool interior = (kv0 + 32 <= q0);
    bf16x8 kf[4];
#pragma unroll
    for (int ks = 0; ks < 4; ++ks)
      kf[ks] = *(const bf16x8*)&QKV[(size_t)(b * NN + kv0 + qc) * QKVN + 512 + ks * 16 + h8];
    bf16x8 vf[2][2];
#pragma unroll
    for (int dblk = 0; dblk < 2; ++dblk)
#pragma unroll
      for (int ks2 = 0; ks2 < 2; ++ks2)
        vf[dblk][ks2] = *(const bf16x8*)&VT[(size_t)(b * 64 + dblk * 32 + qc) * NN + kv0 + ks2 * 16 + h8];
    __builtin_amdgcn_s_setprio(1);
    f32x16 S = {};
#pragma unroll
    for (int ks = 0; ks < 4; ++ks)
      S = __builtin_amdgcn_mfma_f32_32x32x16_bf16(kf[ks], qf[ks], S, 0, 0, 0);
    __builtin_amdgcn_s_setprio(0);
    float sv[16];
    float mx = -1e30f;
    if (interior) {
      f32x4 bv[4];
#pragma unroll
      for (int g = 0; g < 4; ++g)
        bv[g] = *(const f32x4u*)(bt + (q0 + qc - kv0 - 8 * g - 4 * hid - 3));
#pragma unroll
      for (int g = 0; g < 4; ++g)
#pragma unroll
        for (int e = 0; e < 4; ++e) {
          const float val = S[g * 4 + e] + bv[g][3 - e];
          sv[g * 4 + e] = val;
          mx = fmaxf(mx, val);
        }
    } else {
#pragma unroll
      for (int r = 0; r < 16; ++r) {
        const int kvr = (r & 3) + 8 * (r >> 2) + 4 * hid;
        const int d = (q0 + qc) - (kv0 + kvr);
        const int dc = d > 0 ? d : 0;
        float val = S[r] + bt[dc];
        if (d < 0) val = -1e30f;
        sv[r] = val;
        mx = fmaxf(mx, val);
      }
    }
    if (!__all(mx <= m_run + 8.0f)) {
      mx = fmaxf(mx, __shfl_xor(mx, 32));
      const float m_new = fmaxf(m_run, mx);
      const float sc = __expf(m_run - m_new);
      l_run *= sc;
#pragma unroll
      for (int r = 0; r < 16; ++r) { Oacc0[r] *= sc; Oacc1[r] *= sc; }
      m_run = m_new;
    }
    float csum = 0.0f;
#pragma unroll
    for (int r = 0; r < 16; ++r) { sv[r] = __expf(sv[r] - m_run); csum += sv[r]; }
    csum += __shfl_xor(csum, 32);
    l_run += csum;
    int w[8];
#pragma unroll
    for (int g = 0; g < 4; ++g) {
      w[2 * g]     = pack_bf16(sv[4 * g],     sv[4 * g + 1]);
      w[2 * g + 1] = pack_bf16(sv[4 * g + 2], sv[4 * g + 3]);
    }
    bf16x8 pfrag[2];
#pragma unroll
    for (int ks2 = 0; ks2 < 2; ++ks2) {
      const int a  = w[4 * ks2],     bb = w[4 * ks2 + 1];
      const int c  = w[4 * ks2 + 2], dd = w[4 * ks2 + 3];
      const int s0 = hid ? a : c,    s1 = hid ? bb : dd;
      const int r0 = __shfl_xor(s0, 32);
      const int r1 = __shfl_xor(s1, 32);
      i32x4 fw;
      fw[0] = hid ? r0 : a;
      fw[1] = hid ? r1 : bb;
      fw[2] = hid ? c  : r0;
      fw[3] = hid ? dd : r1;
      pfrag[ks2] = __builtin_bit_cast(bf16x8, fw);
    }
    __builtin_amdgcn_s_setprio(1);
#pragma unroll
    for (int ks2 = 0; ks2 < 2; ++ks2) {
      Oacc0 = __builtin_amdgcn_mfma_f32_32x32x16_bf16(vf[0][ks2], pfrag[ks2], Oacc0, 0, 0, 0);
      Oacc1 = __builtin_amdgcn_mfma_f32_32x32x16_bf16(vf[1][ks2], pfrag[ks2], Oacc1, 0, 0, 0);
    }
    __builtin_amdgcn_s_setprio(0);
    kv0 += 32;
  }
  // dl = (r&3) + 8*(r>>2) + 4*hid: groups of 4 consecutive -> bf16x4 stores
#pragma unroll
  for (int g = 0; g < 4; ++g) {
    bf16x4 v0, v1;
#pragma unroll
    for (int j = 0; j < 4; ++j) { v0[j] = (bf16)Oacc0[g * 4 + j]; v1[j] = (bf16)Oacc1[g * 4 + j]; }
    *(bf16x4*)&prow[g * 8 + 4 * hid]      = v0;
    *(bf16x4*)&prow[32 + g * 8 + 4 * hid] = v1;
  }
  if (hid == 0)
    ((float2*)mlbuf)[(size_t)split * AROWS + Rbase + qc] = make_float2(m_run, l_run);
}

// ======================= combine split-KV partials -> O (bf16) =================
// Opart layout: [split][bh][NN q][64 d] bf16 (q-major), dq-fastest thread mapping.
__global__ void attn_combine(const bf16* __restrict__ Opart, const float* __restrict__ mlbuf,
                             bf16* __restrict__ O) {
  const int gtid = blockIdx.x * 256 + threadIdx.x;   // NB*NH*NN*16 threads
  const int dq = gtid & 15;
  const int q  = (gtid >> 4) & (NN - 1);
  const int bh = gtid >> 15;                          // b*NH + h
  const int R = bh * NN + q;
  float2 ml[NSPLIT];
  float m = -1e30f;
#pragma unroll
  for (int s = 0; s < NSPLIT; ++s) {
    ml[s] = ((const float2*)mlbuf)[(size_t)s * AROWS + R];
    m = fmaxf(m, ml[s].x);
  }
  float w[NSPLIT];
  float denom = 0.0f;
#pragma unroll
  for (int s = 0; s < NSPLIT; ++s) {
    w[s] = __expf(ml[s].x - m);
    denom += ml[s].y * w[s];
  }
  const float inv = 1.0f / denom;
  float o[4] = {};
#pragma unroll
  for (int s = 0; s < NSPLIT; ++s) {
    const bf16x4 v = *(const bf16x4*)(Opart + ((size_t)(s * NB * NH + bh) * NN + q) * 64 + dq * 4);
#pragma unroll
    for (int j = 0; j < 4; ++j) o[j] += (float)v[j] * w[s];
  }
  bf16x4 res;
#pragma unroll
  for (int j = 0; j < 4; ++j) res[j] = (bf16)(o[j] * inv);
  const int h = bh & (NH - 1), b = bh >> 3;
  *(bf16x4*)&O[(size_t)(b * NN + q) * INNER + h * DH + dq * 4] = res;
}

// ======================= launch ==========================
extern "C" void kernel_launch(void* const* d_in, const int* in_sizes, int n_in,
                              void* d_out, int out_size, void* d_ws, size_t ws_size,
                              hipStream_t stream) {
  (void)in_sizes; (void)n_in; (void)out_size;
  const float* in_x  = (const float*)d_in[0];
  const float* rel   = (const float*)d_in[1];
  const float* ln1g  = (const float*)d_in[2];
  const float* ln1b  = (const float*)d_in[3];
  const float* wq    = (const float*)d_in[4];
  const float* wkv   = (const float*)d_in[5];
  const float* wo    = (const float*)d_in[6];
  const float* ln2g  = (const float*)d_in[7];
  const float* ln2b  = (const float*)d_in[8];
  const float* w1    = (const float*)d_in[9];
  const float* w2    = (const float*)d_in[10];
  const float* lnfg  = (const float*)d_in[11];
  const float* lnfb  = (const float*)d_in[12];
  float* out = (float*)d_out;

  constexpr size_t E_QKV = (size_t)QKVN * DIM;   // fused wq|wkv, [640][1024]
  constexpr size_t E_WO  = (size_t)DIM * INNER;
  constexpr size_t E_W1F = (size_t)FF2N * DIM;   // interleaved a/g [5632][1024]
  constexpr size_t E_W2  = (size_t)DIM * FFP;
  bf16* wqkvT = (bf16*)d_ws;
  bf16* woT  = wqkvT + NLAY * E_QKV;
  bf16* w1fT = woT  + NLAY * E_WO;
  bf16* w2T  = w1fT + NLAY * E_W1F;
  bf16* xnb  = w2T  + NLAY * E_W2;
  bf16* qkvb = xnb  + (size_t)MROW * DIM;
  bf16* vTb  = qkvb + (size_t)MROW * QKVN;
  bf16* ob   = vTb  + (size_t)NB * 64 * NN;
  bf16* hb   = ob   + (size_t)MROW * INNER;      // FF phase: compact [4096][FFP]
  float* xbuf = (float*)(hb + (size_t)MROW * FF2N);
  float* btab = xbuf + (size_t)MROW * DIM;
  const size_t needed = (size_t)((char*)(btab + NH * NN) - (char*)d_ws);
  if (ws_size < needed) return;  // visible clean failure instead of corruption
  // attn partials overlaid on hb (FF phase and attn phase are disjoint in time):
  // Opart bf16: 8 splits*16 bh*2048 q*64 d*2B = 33.6MB; mlbuf 2.1MB at +34MB (hb 46MB)
  bf16* Opart = hb;
  float* mlbuf = (float*)(hb + (size_t)17 * 1024 * 1024);
  hipMemcpyAsync(xbuf, in_x, (size_t)MROW * DIM * sizeof(float),
                 hipMemcpyDeviceToDevice, stream);
  btab_kernel<<<8, 256, 0, stream>>>(rel, btab);

  const dim3 tb(32, 8);
  conv_tr<<<dim3(16, 32, 6), tb, 0, stream>>>(wq,  (size_t)DIM*INNER, INNER, 0, DIM, INNER,
                                              wqkvT, E_QKV, DIM, 0.125f, -1);  // fold DH^-0.5
  conv_tr<<<dim3(4, 32, 6),  tb, 0, stream>>>(wkv, (size_t)DIM*128, 128, 0, DIM, 128,
                                              wqkvT + (size_t)INNER*DIM, E_QKV, DIM, 1.0f, -1);
  conv_tr<<<dim3(32, 16, 6), tb, 0, stream>>>(wo,  (size_t)INNER*DIM, DIM, 0, INNER, DIM,
                                              woT,  E_WO, INNER, 1.0f, -1);
  conv_tr<<<dim3(88, 32, 6), tb, 0, stream>>>(w1,  (size_t)DIM*2*FF, 2*FF, 0, DIM, FF,
                                              w1fT, E_W1F, DIM, 1.0f, 0);    // a rows -> +0
  conv_tr<<<dim3(88, 32, 6), tb, 0, stream>>>(w1,  (size_t)DIM*2*FF, 2*FF, FF, DIM, FF,
                                              w1fT, E_W1F, DIM, 1.0f, 16);   // g rows -> +16
  conv_tr<<<dim3(32, 88, 6), tb, 0, stream>>>(w2,  (size_t)FF*DIM, DIM, 0, FF, DIM,
                                              w2T,  E_W2, FFP, 1.0f, -1);

  for (int l = 0; l < NLAY; ++l) {
    ln_kernel<bf16><<<MROW, 256, 0, stream>>>(xbuf, ln1g + l*DIM, ln1b + l*DIM, xnb);
    gemm_bt64<4><<<dim3(QKVN/128, MROW/64), 512, 0, stream>>>(xnb, wqkvT + l*E_QKV, DIM, DIM, QKVN, qkvb, (float*)vTb);
    attn_kernel<<<dim3((NN/32)*NSPLIT, NH/4, NB), 256, 0, stream>>>(qkvb, vTb, btab, Opart, mlbuf);
    attn_combine<<<AROWS*16/256, 256, 0, stream>>>(Opart, mlbuf, ob);
    gemm_bt64<1><<<dim3(DIM/128, MROW/64), 512, 0, stream>>>(ob, woT + l*E_WO, INNER, INNER, DIM, nullptr, xbuf);
    ln_kernel<bf16><<<MROW, 256, 0, stream>>>(xbuf, ln2g + l*DIM, ln2b + l*DIM, xnb);
    gemm97<2><<<dim3(FF2N/128, MROW/128), 256, 0, stream>>>(xnb, w1fT + l*E_W1F, DIM, DIM, FFP, hb, nullptr);
    gemm_bt64<1><<<dim3(DIM/128, MROW/64), 512, 0, stream>>>(hb, w2T + l*E_W2, FFP, FFP, DIM, nullptr, xbuf);
  }
  ln_kernel<float><<<MROW, 256, 0, stream>>>(xbuf, lnfg, lnfb, out);
}